// Round 1
// baseline (2582.872 us; speedup 1.0000x reference)
//
#include <hip/hip_runtime.h>

#define NH 16
#define DH 64
#define BB 8
#define LL 1024
#define GG 64

// ---------------- SGEMM: C = A @ W  (K = N = 1024) ----------------
// mode 0: C[m*1024+n]
// mode 1: headed: b=m/Lrows, l=m%Lrows, h=n>>6, d=n&63 -> C[((b*NH+h)*Lrows+l)*64+d]
// mode 2: C[m*1024+n] + bias[n]
__global__ __launch_bounds__(256) void sgemm_k(
    const float* __restrict__ A, const float* __restrict__ W,
    float* __restrict__ C, int mode, const float* __restrict__ bias, int Lrows)
{
    __shared__ float As[16][132];
    __shared__ float Bs[16][132];
    const int tid = threadIdx.x;
    const int bm = blockIdx.x, bn = blockIdx.y;
    const int tr = (tid >> 4) * 8;        // 8 output rows
    const int tc = (tid & 15) * 4;        // 4+4 output cols (at tc and 64+tc)

    float acc[8][8];
#pragma unroll
    for (int i = 0; i < 8; i++)
#pragma unroll
        for (int j = 0; j < 8; j++) acc[i][j] = 0.f;

    const int arow = tid >> 1;            // 0..127
    const int acol = (tid & 1) * 8;       // 0 or 8
    const int brow = tid >> 4;            // 0..15
    const int bc4  = (tid & 15) * 4;

    const float* Ap = A + (size_t)(bm * 128 + arow) * 1024 + acol;
    const float* Wp = W + (size_t)brow * 1024 + bn * 128 + bc4;

    for (int kt = 0; kt < 1024; kt += 16) {
        float4 a0 = *(const float4*)(Ap + kt);
        float4 a1 = *(const float4*)(Ap + kt + 4);
        float4 b0 = *(const float4*)(Wp + (size_t)kt * 1024);
        float4 b1 = *(const float4*)(Wp + (size_t)kt * 1024 + 64);
        __syncthreads();
        As[acol + 0][arow] = a0.x; As[acol + 1][arow] = a0.y;
        As[acol + 2][arow] = a0.z; As[acol + 3][arow] = a0.w;
        As[acol + 4][arow] = a1.x; As[acol + 5][arow] = a1.y;
        As[acol + 6][arow] = a1.z; As[acol + 7][arow] = a1.w;
        *(float4*)&Bs[brow][bc4]      = b0;
        *(float4*)&Bs[brow][64 + bc4] = b1;
        __syncthreads();
#pragma unroll
        for (int k = 0; k < 16; k++) {
            float4 x0 = *(const float4*)&As[k][tr];
            float4 x1 = *(const float4*)&As[k][tr + 4];
            float4 y0 = *(const float4*)&Bs[k][tc];
            float4 y1 = *(const float4*)&Bs[k][64 + tc];
            float xv[8] = {x0.x, x0.y, x0.z, x0.w, x1.x, x1.y, x1.z, x1.w};
            float yv[8] = {y0.x, y0.y, y0.z, y0.w, y1.x, y1.y, y1.z, y1.w};
#pragma unroll
            for (int i = 0; i < 8; i++)
#pragma unroll
                for (int j = 0; j < 8; j++) acc[i][j] += xv[i] * yv[j];
        }
    }

#pragma unroll
    for (int i = 0; i < 8; i++) {
        int m = bm * 128 + tr + i;
        if (mode == 1) {
            int b = m / Lrows, l = m % Lrows;
#pragma unroll
            for (int g = 0; g < 2; g++) {
                int n0 = bn * 128 + g * 64 + tc;
                int hh = n0 >> 6, d = n0 & 63;
                float4 v = make_float4(acc[i][g * 4 + 0], acc[i][g * 4 + 1],
                                       acc[i][g * 4 + 2], acc[i][g * 4 + 3]);
                *(float4*)&C[((size_t)(b * NH + hh) * Lrows + l) * 64 + d] = v;
            }
        } else {
#pragma unroll
            for (int g = 0; g < 2; g++) {
                int n0 = bn * 128 + g * 64 + tc;
                float4 v = make_float4(acc[i][g * 4 + 0], acc[i][g * 4 + 1],
                                       acc[i][g * 4 + 2], acc[i][g * 4 + 3]);
                if (mode == 2) {
                    float4 bv = *(const float4*)&bias[n0];
                    v.x += bv.x; v.y += bv.y; v.z += bv.z; v.w += bv.w;
                }
                *(float4*)&C[(size_t)m * 1024 + n0] = v;
            }
        }
    }
}

// ---------------- W_ep[b,h][d][e] = sum_g rq[g][d] * rk[g][e] ----------------
__global__ __launch_bounds__(256) void wep_k(
    const float* __restrict__ RQ, const float* __restrict__ RK, float* __restrict__ WEP)
{
    const int bh = blockIdx.x;
    __shared__ float rqs[4096];
    __shared__ float rks[4096];
    const int tid = threadIdx.x;
    const float4* rq4 = (const float4*)(RQ + (size_t)bh * 4096);
    const float4* rk4 = (const float4*)(RK + (size_t)bh * 4096);
#pragma unroll
    for (int j = 0; j < 4; j++) {
        ((float4*)rqs)[tid + 256 * j] = rq4[tid + 256 * j];
        ((float4*)rks)[tid + 256 * j] = rk4[tid + 256 * j];
    }
    __syncthreads();
    const int dd = tid >> 2, q = (tid & 3) * 16;
    float acc[16];
#pragma unroll
    for (int i = 0; i < 16; i++) acc[i] = 0.f;
    for (int g = 0; g < 64; g++) {
        float a = rqs[g * 64 + dd];
#pragma unroll
        for (int i = 0; i < 16; i++) acc[i] += a * rks[g * 64 + q + i];
    }
    float* out = WEP + (size_t)bh * 4096 + dd * 64 + q;
#pragma unroll
    for (int i4 = 0; i4 < 4; i4++)
        *(float4*)&out[i4 * 4] =
            make_float4(acc[i4 * 4], acc[i4 * 4 + 1], acc[i4 * 4 + 2], acc[i4 * 4 + 3]);
}

// ---------------- fused (q@Wep)@k^T -> online softmax -> @v, transposed out ----------------
#define LP 68  // padded LDS row stride (floats); 68*4B = 17*16B keeps float4 alignment
__global__ __launch_bounds__(256) void attn_k(
    const float* __restrict__ Qh, const float* __restrict__ Kh,
    const float* __restrict__ Vh, const float* __restrict__ WEP,
    float* __restrict__ O2)
{
    const int l0 = blockIdx.x * 64;
    const int h = blockIdx.y, b = blockIdx.z;
    const int bh = b * NH + h;
    __shared__ float qs[64 * LP];
    __shared__ float ks[64 * LP];   // reused: K-tile -> p-buffer -> out-transpose buffer
    __shared__ float vs[64 * LP];
    const int tid = threadIdx.x;
    const int rg = tid >> 4;   // 0..15 -> rows rg*4..rg*4+3
    const int ln = tid & 15;   // 0..15

    // ---- prologue: qw = Qtile @ Wep[bh] into qs ----
    {
        const float4* qsrc = (const float4*)(Qh + ((size_t)bh * LL + l0) * 64);
        const float4* wsrc = (const float4*)(WEP + (size_t)bh * 4096);
#pragma unroll
        for (int j = 0; j < 4; j++) {
            int f4 = tid + 256 * j;
            int row = f4 >> 4, col4 = (f4 & 15);
            ((float4*)(ks + row * LP))[col4] = qsrc[f4];
            ((float4*)(vs + row * LP))[col4] = wsrc[f4];
        }
        __syncthreads();
        float4 qw[4];
#pragma unroll
        for (int ri = 0; ri < 4; ri++) qw[ri] = make_float4(0.f, 0.f, 0.f, 0.f);
        for (int e = 0; e < 64; e++) {
            float4 w4 = *(const float4*)&vs[e * LP + ln * 4];
#pragma unroll
            for (int ri = 0; ri < 4; ri++) {
                float qv = ks[(rg * 4 + ri) * LP + e];
                qw[ri].x += qv * w4.x; qw[ri].y += qv * w4.y;
                qw[ri].z += qv * w4.z; qw[ri].w += qv * w4.w;
            }
        }
#pragma unroll
        for (int ri = 0; ri < 4; ri++)
            *(float4*)&qs[(rg * 4 + ri) * LP + ln * 4] = qw[ri];
        // qs-write / ks-reuse hazards covered by the syncs inside the main loop
    }

    float m_run[4], l_sum[4];
    float4 o4[4];
#pragma unroll
    for (int ri = 0; ri < 4; ri++) {
        m_run[ri] = -__builtin_inff(); l_sum[ri] = 0.f;
        o4[ri] = make_float4(0.f, 0.f, 0.f, 0.f);
    }

    const float4* qs4 = (const float4*)qs;
    const float4* ks4 = (const float4*)ks;
    const float4* vs4 = (const float4*)vs;

    for (int s0 = 0; s0 < LL; s0 += 64) {
        __syncthreads();  // all reads of ks/vs (prev chunk / prologue) done
        const float4* ksrc = (const float4*)(Kh + ((size_t)bh * LL + s0) * 64);
        const float4* vsrc = (const float4*)(Vh + ((size_t)bh * LL + s0) * 64);
#pragma unroll
        for (int j = 0; j < 4; j++) {
            int f4 = tid + 256 * j;
            int row = f4 >> 4, col4 = (f4 & 15);
            ((float4*)(ks + row * LP))[col4] = ksrc[f4];
            ((float4*)(vs + row * LP))[col4] = vsrc[f4];
        }
        __syncthreads();

        // scores: rows rg*4+ri, cols ci*16+ln
        float sc[4][4];
#pragma unroll
        for (int ri = 0; ri < 4; ri++)
#pragma unroll
            for (int ci = 0; ci < 4; ci++) sc[ri][ci] = 0.f;
#pragma unroll
        for (int e4 = 0; e4 < 16; e4++) {
            float4 qv[4], kv[4];
#pragma unroll
            for (int ri = 0; ri < 4; ri++) qv[ri] = qs4[(rg * 4 + ri) * 17 + e4];
#pragma unroll
            for (int ci = 0; ci < 4; ci++) kv[ci] = ks4[(ci * 16 + ln) * 17 + e4];
#pragma unroll
            for (int ri = 0; ri < 4; ri++)
#pragma unroll
                for (int ci = 0; ci < 4; ci++)
                    sc[ri][ci] += qv[ri].x * kv[ci].x + qv[ri].y * kv[ci].y +
                                  qv[ri].z * kv[ci].z + qv[ri].w * kv[ci].w;
        }

        float p[4][4];
#pragma unroll
        for (int ri = 0; ri < 4; ri++) {
#pragma unroll
            for (int ci = 0; ci < 4; ci++) sc[ri][ci] *= 0.125f;
            float mx = fmaxf(fmaxf(sc[ri][0], sc[ri][1]), fmaxf(sc[ri][2], sc[ri][3]));
            mx = fmaxf(mx, __shfl_xor(mx, 1));
            mx = fmaxf(mx, __shfl_xor(mx, 2));
            mx = fmaxf(mx, __shfl_xor(mx, 4));
            mx = fmaxf(mx, __shfl_xor(mx, 8));
            float m_new = fmaxf(m_run[ri], mx);
            float alpha = __expf(m_run[ri] - m_new);
            float ls = 0.f;
#pragma unroll
            for (int ci = 0; ci < 4; ci++) {
                p[ri][ci] = __expf(sc[ri][ci] - m_new);
                ls += p[ri][ci];
            }
            ls += __shfl_xor(ls, 1);
            ls += __shfl_xor(ls, 2);
            ls += __shfl_xor(ls, 4);
            ls += __shfl_xor(ls, 8);
            l_sum[ri] = l_sum[ri] * alpha + ls;
            m_run[ri] = m_new;
            o4[ri].x *= alpha; o4[ri].y *= alpha; o4[ri].z *= alpha; o4[ri].w *= alpha;
        }

        __syncthreads();  // done reading ks (scores); reuse as p-buffer
#pragma unroll
        for (int ri = 0; ri < 4; ri++)
#pragma unroll
            for (int ci = 0; ci < 4; ci++)
                ks[(rg * 4 + ri) * LP + ci * 16 + ln] = p[ri][ci];
        __syncthreads();

        // PV: o[r][d] += sum_c p[r][c] * v[c][d],  d = ln*4..ln*4+3
#pragma unroll
        for (int c4 = 0; c4 < 16; c4++) {
            float4 pr[4];
#pragma unroll
            for (int ri = 0; ri < 4; ri++) pr[ri] = ks4[(rg * 4 + ri) * 17 + c4];
            float4 v0 = vs4[(c4 * 4 + 0) * 17 + ln];
            float4 v1 = vs4[(c4 * 4 + 1) * 17 + ln];
            float4 v2 = vs4[(c4 * 4 + 2) * 17 + ln];
            float4 v3 = vs4[(c4 * 4 + 3) * 17 + ln];
#pragma unroll
            for (int ri = 0; ri < 4; ri++) {
                o4[ri].x += pr[ri].x * v0.x + pr[ri].y * v1.x + pr[ri].z * v2.x + pr[ri].w * v3.x;
                o4[ri].y += pr[ri].x * v0.y + pr[ri].y * v1.y + pr[ri].z * v2.y + pr[ri].w * v3.y;
                o4[ri].z += pr[ri].x * v0.z + pr[ri].y * v1.z + pr[ri].z * v2.z + pr[ri].w * v3.z;
                o4[ri].w += pr[ri].x * v0.w + pr[ri].y * v1.w + pr[ri].z * v2.w + pr[ri].w * v3.w;
            }
        }
    }

    // normalize, transpose through LDS, store O2[b][h*64+d][l]
    __syncthreads();
#pragma unroll
    for (int ri = 0; ri < 4; ri++) {
        float inv = 1.f / l_sum[ri];
        float4 ov = make_float4(o4[ri].x * inv, o4[ri].y * inv, o4[ri].z * inv, o4[ri].w * inv);
        *(float4*)&ks[(rg * 4 + ri) * LP + ln * 4] = ov;
    }
    __syncthreads();
    const int d = tid >> 2, lq = tid & 3;
    float tmp[16];
#pragma unroll
    for (int i = 0; i < 16; i++) tmp[i] = ks[(lq * 16 + i) * LP + d];
    float* dst = O2 + ((size_t)b * 1024 + h * 64 + d) * 1024 + l0 + lq * 16;
#pragma unroll
    for (int i4 = 0; i4 < 4; i4++)
        *(float4*)&dst[i4 * 4] =
            make_float4(tmp[i4 * 4], tmp[i4 * 4 + 1], tmp[i4 * 4 + 2], tmp[i4 * 4 + 3]);
}

extern "C" void kernel_launch(void* const* d_in, const int* in_sizes, int n_in,
                              void* d_out, int out_size, void* d_ws, size_t ws_size,
                              hipStream_t stream) {
    const float* queries = (const float*)d_in[0];
    const float* keys    = (const float*)d_in[1];
    const float* values  = (const float*)d_in[2];
    const float* routers = (const float*)d_in[3];
    const float* Wq  = (const float*)d_in[4];
    const float* Wk  = (const float*)d_in[5];
    const float* Wv  = (const float*)d_in[6];
    const float* Wlq = (const float*)d_in[7];
    const float* Wlk = (const float*)d_in[8];
    const float* Wo  = (const float*)d_in[9];
    const float* bo  = (const float*)d_in[10];
    float* out = (float*)d_out;

    float* ws = (float*)d_ws;
    float* Q   = ws;                       // [B,H,L,64]   8388608
    float* K   = ws + 8388608;             // [B,H,S,64]   8388608
    float* V   = ws + 16777216;            // [B,H,S,64]   8388608
    float* RQ  = ws + 25165824;            // [B,H,G,64]    524288
    float* RK  = ws + 25690112;            // [B,H,G,64]    524288
    float* WEP = ws + 26214400;            // [B,H,64,64]   524288
    float* O2  = ws + 26738688;            // [B,1024(h*64+d),L] 8388608

    dim3 blk(256);
    sgemm_k<<<dim3(64, 8), blk, 0, stream>>>(queries, Wq, Q, 1, nullptr, LL);
    sgemm_k<<<dim3(64, 8), blk, 0, stream>>>(keys,    Wk, K, 1, nullptr, LL);
    sgemm_k<<<dim3(64, 8), blk, 0, stream>>>(values,  Wv, V, 1, nullptr, LL);
    sgemm_k<<<dim3(4, 8),  blk, 0, stream>>>(routers, Wlq, RQ, 1, nullptr, GG);
    sgemm_k<<<dim3(4, 8),  blk, 0, stream>>>(routers, Wlk, RK, 1, nullptr, GG);
    wep_k<<<dim3(BB * NH), blk, 0, stream>>>(RQ, RK, WEP);
    attn_k<<<dim3(LL / 64, NH, BB), blk, 0, stream>>>(Q, K, V, WEP, O2);
    sgemm_k<<<dim3(64, 8), blk, 0, stream>>>(O2, Wo, out, 2, bo, LL);
}

// Round 3
// 827.492 us; speedup vs baseline: 3.1213x; 3.1213x over previous
//
#include <hip/hip_runtime.h>

typedef __bf16 bf16;
typedef short s8v __attribute__((ext_vector_type(8)));    // 8 bf16 as shorts (4 VGPR) - MFMA A/B frag
typedef float f4v __attribute__((ext_vector_type(4)));    // MFMA C/D frag
typedef bf16 bf4v __attribute__((ext_vector_type(4)));
typedef bf16 bf8v __attribute__((ext_vector_type(8)));

#define NH 16
#define BB 8
#define QWSCALE 0.18033688011112043f  /* 0.125 * log2(e): scores in exp2 domain */

__device__ __forceinline__ void glds16(void* lds, const void* g) {
    __builtin_amdgcn_global_load_lds(
        (const __attribute__((address_space(1))) unsigned int*)g,
        (__attribute__((address_space(3))) unsigned int*)lds, 16, 0, 0);
}

// ---------------- fp32 SGEMM (routers only): C = A @ W, K=N=1024 ----------------
__global__ __launch_bounds__(256) void sgemm_k(
    const float* __restrict__ A, const float* __restrict__ W,
    float* __restrict__ C, int mode, const float* __restrict__ bias, int Lrows)
{
    __shared__ float As[16][132];
    __shared__ float Bs[16][132];
    const int tid = threadIdx.x;
    const int bm = blockIdx.x, bn = blockIdx.y;
    const int tr = (tid >> 4) * 8;
    const int tc = (tid & 15) * 4;

    float acc[8][8];
#pragma unroll
    for (int i = 0; i < 8; i++)
#pragma unroll
        for (int j = 0; j < 8; j++) acc[i][j] = 0.f;

    const int arow = tid >> 1;
    const int acol = (tid & 1) * 8;
    const int brow = tid >> 4;
    const int bc4  = (tid & 15) * 4;

    const float* Ap = A + (size_t)(bm * 128 + arow) * 1024 + acol;
    const float* Wp = W + (size_t)brow * 1024 + bn * 128 + bc4;

    for (int kt = 0; kt < 1024; kt += 16) {
        float4 a0 = *(const float4*)(Ap + kt);
        float4 a1 = *(const float4*)(Ap + kt + 4);
        float4 b0 = *(const float4*)(Wp + (size_t)kt * 1024);
        float4 b1 = *(const float4*)(Wp + (size_t)kt * 1024 + 64);
        __syncthreads();
        As[acol + 0][arow] = a0.x; As[acol + 1][arow] = a0.y;
        As[acol + 2][arow] = a0.z; As[acol + 3][arow] = a0.w;
        As[acol + 4][arow] = a1.x; As[acol + 5][arow] = a1.y;
        As[acol + 6][arow] = a1.z; As[acol + 7][arow] = a1.w;
        *(float4*)&Bs[brow][bc4]      = b0;
        *(float4*)&Bs[brow][64 + bc4] = b1;
        __syncthreads();
#pragma unroll
        for (int k = 0; k < 16; k++) {
            float4 x0 = *(const float4*)&As[k][tr];
            float4 x1 = *(const float4*)&As[k][tr + 4];
            float4 y0 = *(const float4*)&Bs[k][tc];
            float4 y1 = *(const float4*)&Bs[k][64 + tc];
            float xv[8] = {x0.x, x0.y, x0.z, x0.w, x1.x, x1.y, x1.z, x1.w};
            float yv[8] = {y0.x, y0.y, y0.z, y0.w, y1.x, y1.y, y1.z, y1.w};
#pragma unroll
            for (int i = 0; i < 8; i++)
#pragma unroll
                for (int j = 0; j < 8; j++) acc[i][j] += xv[i] * yv[j];
        }
    }

#pragma unroll
    for (int i = 0; i < 8; i++) {
        int m = bm * 128 + tr + i;
        if (mode == 1) {
            int b = m / Lrows, l = m % Lrows;
#pragma unroll
            for (int g = 0; g < 2; g++) {
                int n0 = bn * 128 + g * 64 + tc;
                int hh = n0 >> 6, d = n0 & 63;
                float4 v = make_float4(acc[i][g * 4 + 0], acc[i][g * 4 + 1],
                                       acc[i][g * 4 + 2], acc[i][g * 4 + 3]);
                *(float4*)&C[((size_t)(b * NH + hh) * Lrows + l) * 64 + d] = v;
            }
        } else {
#pragma unroll
            for (int g = 0; g < 2; g++) {
                int n0 = bn * 128 + g * 64 + tc;
                float4 v = make_float4(acc[i][g * 4 + 0], acc[i][g * 4 + 1],
                                       acc[i][g * 4 + 2], acc[i][g * 4 + 3]);
                if (mode == 2) {
                    float4 bv = *(const float4*)&bias[n0];
                    v.x += bv.x; v.y += bv.y; v.z += bv.z; v.w += bv.w;
                }
                *(float4*)&C[(size_t)m * 1024 + n0] = v;
            }
        }
    }
}

// ---------------- W_ep[b,h][d][e] = sum_g rq[g][d] * rk[g][e]  (fp32) ----------------
__global__ __launch_bounds__(256) void wep_k(
    const float* __restrict__ RQ, const float* __restrict__ RK, float* __restrict__ WEP)
{
    const int bh = blockIdx.x;
    __shared__ float rqs[4096];
    __shared__ float rks[4096];
    const int tid = threadIdx.x;
    const float4* rq4 = (const float4*)(RQ + (size_t)bh * 4096);
    const float4* rk4 = (const float4*)(RK + (size_t)bh * 4096);
#pragma unroll
    for (int j = 0; j < 4; j++) {
        ((float4*)rqs)[tid + 256 * j] = rq4[tid + 256 * j];
        ((float4*)rks)[tid + 256 * j] = rk4[tid + 256 * j];
    }
    __syncthreads();
    const int dd = tid >> 2, q = (tid & 3) * 16;
    float acc[16];
#pragma unroll
    for (int i = 0; i < 16; i++) acc[i] = 0.f;
    for (int g = 0; g < 64; g++) {
        float a = rqs[g * 64 + dd];
#pragma unroll
        for (int i = 0; i < 16; i++) acc[i] += a * rks[g * 64 + q + i];
    }
    float* out = WEP + (size_t)bh * 4096 + dd * 64 + q;
#pragma unroll
    for (int i4 = 0; i4 < 4; i4++)
        *(float4*)&out[i4 * 4] =
            make_float4(acc[i4 * 4], acc[i4 * 4 + 1], acc[i4 * 4 + 2], acc[i4 * 4 + 3]);
}

// -------- WqWepT hi/lo [b][n=h*64+e][k=D] = scale * sum_d Wep[b,h][d][e] * Wq[D][h*64+d] --------
__global__ __launch_bounds__(256) void wqwep_k(
    const float* __restrict__ Wq, const float* __restrict__ WEP,
    bf16* __restrict__ Thi, bf16* __restrict__ Tlo)
{
    const int b = blockIdx.x >> 4, h = blockIdx.x & 15;
    __shared__ float weps[4096];       // [d][e]
    __shared__ float wqs[128 * 68];    // [Dloc][d]
    const int tid = threadIdx.x;
    const float4* wsrc = (const float4*)(WEP + (size_t)blockIdx.x * 4096);
#pragma unroll
    for (int it = 0; it < 4; it++)
        ((float4*)weps)[it * 256 + tid] = wsrc[it * 256 + tid];
    const int Dloc = tid >> 1, e0 = (tid & 1) * 32;
    for (int Dt = 0; Dt < 8; Dt++) {
        __syncthreads();
#pragma unroll
        for (int it = 0; it < 8; it++) {
            int g = it * 256 + tid;
            int r = g >> 4, c = (g & 15) * 4;
            *(float4*)&wqs[r * 68 + c] =
                *(const float4*)&Wq[(size_t)(Dt * 128 + r) * 1024 + h * 64 + c];
        }
        __syncthreads();
        float acc[32];
#pragma unroll
        for (int e = 0; e < 32; e++) acc[e] = 0.f;
        for (int d = 0; d < 64; d++) {
            float a = wqs[Dloc * 68 + d];
            const float* wr = &weps[d * 64 + e0];
#pragma unroll
            for (int e = 0; e < 32; e++) acc[e] += a * wr[e];
        }
        int D = Dt * 128 + Dloc;
        size_t row0 = (size_t)b * 1024 + h * 64 + e0;
#pragma unroll
        for (int e = 0; e < 32; e++) {
            float v = acc[e] * QWSCALE;
            bf16 hv = (bf16)v;
            Thi[(row0 + e) * 1024 + D] = hv;
            Tlo[(row0 + e) * 1024 + D] = (bf16)(v - (float)hv);
        }
    }
}

// ---------------- split/cast fp32 -> bf16 hi (+lo) ----------------
__global__ void split_cast_k(const float* __restrict__ x, bf16* __restrict__ hi,
                             bf16* __restrict__ lo, int n4)
{
    int idx = blockIdx.x * blockDim.x + threadIdx.x;
    int stride = gridDim.x * blockDim.x;
    for (int i = idx; i < n4; i += stride) {
        float4 v = ((const float4*)x)[i];
        bf4v h;
        h[0] = (bf16)v.x; h[1] = (bf16)v.y; h[2] = (bf16)v.z; h[3] = (bf16)v.w;
        ((bf4v*)hi)[i] = h;
        if (lo) {
            bf4v l;
            l[0] = (bf16)(v.x - (float)h[0]);
            l[1] = (bf16)(v.y - (float)h[1]);
            l[2] = (bf16)(v.z - (float)h[2]);
            l[3] = (bf16)(v.w - (float)h[3]);
            ((bf4v*)lo)[i] = l;
        }
    }
}

// ------- transpose fp32 W[k][n] -> bf16 WT[n][k] (1024x1024), optional hi/lo split -------
__global__ __launch_bounds__(256) void transw_k(const float* __restrict__ W,
                                                bf16* __restrict__ WT, bf16* __restrict__ WTlo)
{
    __shared__ float T[64 * 68];
    const int k0 = blockIdx.x * 64, n0 = blockIdx.y * 64;
    const int tid = threadIdx.x;
#pragma unroll
    for (int it = 0; it < 4; it++) {
        int g = it * 256 + tid;
        int r = g >> 4, c = (g & 15) * 4;
        *(float4*)&T[r * 68 + c] = *(const float4*)&W[(size_t)(k0 + r) * 1024 + n0 + c];
    }
    __syncthreads();
#pragma unroll
    for (int it = 0; it < 4; it++) {
        int g = it * 256 + tid;
        int n = g >> 4, k4 = (g & 15) * 4;
        bf4v o, ol;
#pragma unroll
        for (int t = 0; t < 4; t++) {
            float v = T[(k4 + t) * 68 + n];
            o[t] = (bf16)v;
            ol[t] = (bf16)(v - (float)o[t]);
        }
        *(bf4v*)&WT[(size_t)(n0 + n) * 1024 + k0 + k4] = o;
        if (WTlo) *(bf4v*)&WTlo[(size_t)(n0 + n) * 1024 + k0 + k4] = ol;
    }
}

// ---------------- bf16 MFMA GEMM: C[m][n] = A[m][k] @ Bt[n][k]^T, M=8192, N=K=1024 ----------------
// PASSES=3: A and B both hi/lo split: acc = AhiBhi + AloBhi + AhiBlo (drop lo*lo).
// outmode 0: fp32 out[m*1024+n] + bias[n]
// outmode 1: split-headed bf16: outH/outL[((b*16+h)*1024+l)*64+e]
// outmode 2: VT bf16: outH[((b*16+h)*64+d)*1024+s]
template<int PASSES>
__global__ __launch_bounds__(256, 2) void gemm_k(
    const bf16* __restrict__ A, const bf16* __restrict__ Alo,
    const bf16* __restrict__ Bt, const bf16* __restrict__ Btlo,
    int bBatched, int outmode,
    float* __restrict__ outF, const float* __restrict__ bias,
    bf16* __restrict__ outH, bf16* __restrict__ outL)
{
    __shared__ bf16 Ah[128 * 64];
    __shared__ bf16 Bh[128 * 64];
    __shared__ bf16 Al[(PASSES == 3) ? 128 * 64 : 64];
    __shared__ bf16 Bl[(PASSES == 3) ? 128 * 64 : 64];
    const int tid = threadIdx.x;
    const int bm = blockIdx.x, bn = blockIdx.y;
    const size_t boff = bBatched ? ((size_t)(bm >> 3) << 20) : (size_t)0;
    const bf16* Bt_b = Bt + boff;
    const bf16* Btlo_b = (PASSES == 3) ? (Btlo + boff) : nullptr;
    const int li = tid & 15;
    const int qq = (tid >> 4) & 3;
    const int wave = tid >> 6;
    const int wm0 = (wave & 1) * 64, wn0 = (wave >> 1) * 64;

    f4v acc[4][4];
    f4v zf; zf[0] = 0.f; zf[1] = 0.f; zf[2] = 0.f; zf[3] = 0.f;
#pragma unroll
    for (int mt = 0; mt < 4; mt++)
#pragma unroll
        for (int nt = 0; nt < 4; nt++) acc[mt][nt] = zf;

    for (int kt = 0; kt < 16; kt++) {
        const int col0 = kt * 64;
#pragma unroll
        for (int it = 0; it < 4; it++) {
            int g = it * 256 + tid;
            int r = g >> 3, p = g & 7;
            int gcol = col0 + ((p ^ (r & 7)) << 3);
            int ldsoff = (g & ~63) << 3;
            size_t ga = (size_t)(bm * 128 + r) * 1024 + gcol;
            size_t gb = (size_t)(bn * 128 + r) * 1024 + gcol;
            glds16(Ah + ldsoff, A + ga);
            glds16(Bh + ldsoff, Bt_b + gb);
            if (PASSES == 3) {
                glds16(Al + ldsoff, Alo + ga);
                glds16(Bl + ldsoff, Btlo_b + gb);
            }
        }
        __syncthreads();
#pragma unroll
        for (int ks = 0; ks < 2; ks++) {
            s8v af[4], alf[4], bhf[4], blf[4];
#pragma unroll
            for (int mt = 0; mt < 4; mt++) {
                int row = wm0 + mt * 16 + li;
                int off = row * 64 + (((ks * 4 + qq) ^ (li & 7)) << 3);
                af[mt] = *(const s8v*)&Ah[off];
                if (PASSES == 3) alf[mt] = *(const s8v*)&Al[off];
            }
#pragma unroll
            for (int nt = 0; nt < 4; nt++) {
                int row = wn0 + nt * 16 + li;
                int off = row * 64 + (((ks * 4 + qq) ^ (li & 7)) << 3);
                bhf[nt] = *(const s8v*)&Bh[off];
                if (PASSES == 3) blf[nt] = *(const s8v*)&Bl[off];
            }
#pragma unroll
            for (int mt = 0; mt < 4; mt++)
#pragma unroll
                for (int nt = 0; nt < 4; nt++) {
                    acc[mt][nt] = __builtin_amdgcn_mfma_f32_16x16x32_bf16(
                        af[mt], bhf[nt], acc[mt][nt], 0, 0, 0);
                    if (PASSES == 3) {
                        acc[mt][nt] = __builtin_amdgcn_mfma_f32_16x16x32_bf16(
                            alf[mt], bhf[nt], acc[mt][nt], 0, 0, 0);
                        acc[mt][nt] = __builtin_amdgcn_mfma_f32_16x16x32_bf16(
                            af[mt], blf[nt], acc[mt][nt], 0, 0, 0);
                    }
                }
        }
        __syncthreads();
    }

    // epilogue
#pragma unroll
    for (int mt = 0; mt < 4; mt++) {
#pragma unroll
        for (int nt = 0; nt < 4; nt++) {
            int n = bn * 128 + wn0 + nt * 16 + li;
            int m0 = bm * 128 + wm0 + mt * 16 + qq * 4;
            if (outmode == 0) {
                float bv = bias[n];
#pragma unroll
                for (int rg = 0; rg < 4; rg++)
                    outF[(size_t)(m0 + rg) * 1024 + n] = acc[mt][nt][rg] + bv;
            } else if (outmode == 1) {
                int h = n >> 6, e = n & 63;
#pragma unroll
                for (int rg = 0; rg < 4; rg++) {
                    int m = m0 + rg;
                    int b = m >> 10, l = m & 1023;
                    size_t idx = ((size_t)(b * NH + h) * 1024 + l) * 64 + e;
                    float v = acc[mt][nt][rg];
                    bf16 hv = (bf16)v;
                    outH[idx] = hv;
                    outL[idx] = (bf16)(v - (float)hv);
                }
            } else {
                int b = m0 >> 10, s = m0 & 1023;
                int h = n >> 6, d = n & 63;
                bf4v v;
                v[0] = (bf16)acc[mt][nt][0]; v[1] = (bf16)acc[mt][nt][1];
                v[2] = (bf16)acc[mt][nt][2]; v[3] = (bf16)acc[mt][nt][3];
                *(bf4v*)&outH[((size_t)(b * NH + h) * 64 + d) * 1024 + s] = v;
            }
        }
    }
}

// ---------------- fused attention: S^T = Kp·Qw^T 3-pass, online softmax, O^T = V^T·P^T ----------------
// Output layout honors the reference's reshape quirk: O[b][h*64+d][l]  (K-dim of final GEMM = l)
__global__ __launch_bounds__(256, 2) void attn_k(
    const bf16* __restrict__ QwHi, const bf16* __restrict__ QwLo,
    const bf16* __restrict__ KpHi, const bf16* __restrict__ KpLo,
    const bf16* __restrict__ VT, bf16* __restrict__ O)
{
    __shared__ bf16 Qh[128 * 64];
    __shared__ bf16 Ql[128 * 64];
    __shared__ __align__(16) char scratch[43008];
    bf16* Kh = (bf16*)scratch;          // [64][64]
    bf16* Kl = Kh + 4096;               // [64][64]
    bf16* Vt = Kh + 8192;               // [64 d][64 s]
    bf16* Pb = Kh + 12288;              // [128 r][stride 72]
    float* Obuf = (float*)scratch;      // [64 d][stride 132] (epilogue reuse)

    const int tid = threadIdx.x;
    const int l0 = blockIdx.x * 128;
    const int bh = blockIdx.z * NH + blockIdx.y;
    const int li = tid & 15;
    const int qq = (tid >> 4) & 3;
    const int wave = tid >> 6;
    const int r0w = wave * 32;

    // prologue: stage Qw hi/lo tile [128 l][64 e] (xor-swizzled)
    const bf16* qhsrc = QwHi + ((size_t)bh * 1024 + l0) * 64;
    const bf16* qlsrc = QwLo + ((size_t)bh * 1024 + l0) * 64;
#pragma unroll
    for (int it = 0; it < 8; it++) {
        int g = it * 256 + tid;
        int buf = g >> 10;
        int L = g & 1023;
        int r = L >> 3, p = L & 7;
        int goff = r * 64 + ((p ^ (r & 7)) << 3);
        glds16((buf ? Ql : Qh) + ((L & ~63) << 3), (buf ? qlsrc : qhsrc) + goff);
    }

    float mrun[2], lsum[2];
    mrun[0] = -__builtin_inff(); mrun[1] = -__builtin_inff();
    lsum[0] = 0.f; lsum[1] = 0.f;
    f4v accO[4][2];
    {
        f4v zf; zf[0] = 0.f; zf[1] = 0.f; zf[2] = 0.f; zf[3] = 0.f;
#pragma unroll
        for (int dt = 0; dt < 4; dt++) { accO[dt][0] = zf; accO[dt][1] = zf; }
    }

    for (int s0 = 0; s0 < 1024; s0 += 64) {
        __syncthreads();  // previous chunk's K/V/P reads done (also drains prologue loads)
#pragma unroll
        for (int it = 0; it < 6; it++) {
            int g = it * 256 + tid;
            int buf = g >> 9;
            int L = g & 511;
            int r = L >> 3, p = L & 7;
            int blk = (p ^ (r & 7)) << 3;
            const bf16* src;
            bf16* dstb;
            if (buf == 0)      { src = KpHi + ((size_t)bh * 1024 + s0 + r) * 64 + blk; dstb = Kh; }
            else if (buf == 1) { src = KpLo + ((size_t)bh * 1024 + s0 + r) * 64 + blk; dstb = Kl; }
            else               { src = VT + ((size_t)bh * 64 + r) * 1024 + s0 + blk;   dstb = Vt; }
            glds16(dstb + ((L & ~63) << 3), src);
        }
        __syncthreads();

        // scores: accS[ct][rt] = S^T tile; S^T rows c = ct*16+qq*4+rg, cols r = r0w+rt*16+li
        f4v accS[4][2];
        {
            f4v zf; zf[0] = 0.f; zf[1] = 0.f; zf[2] = 0.f; zf[3] = 0.f;
#pragma unroll
            for (int ct = 0; ct < 4; ct++) { accS[ct][0] = zf; accS[ct][1] = zf; }
        }
#pragma unroll
        for (int ks = 0; ks < 2; ks++) {
            s8v khf[4], klf[4], qhf[2], qlf[2];
#pragma unroll
            for (int ct = 0; ct < 4; ct++) {
                int row = ct * 16 + li;
                int off = row * 64 + (((ks * 4 + qq) ^ (li & 7)) << 3);
                khf[ct] = *(const s8v*)&Kh[off];
                klf[ct] = *(const s8v*)&Kl[off];
            }
#pragma unroll
            for (int rt = 0; rt < 2; rt++) {
                int row = r0w + rt * 16 + li;
                int off = row * 64 + (((ks * 4 + qq) ^ (li & 7)) << 3);
                qhf[rt] = *(const s8v*)&Qh[off];
                qlf[rt] = *(const s8v*)&Ql[off];
            }
#pragma unroll
            for (int ct = 0; ct < 4; ct++)
#pragma unroll
                for (int rt = 0; rt < 2; rt++) {
                    accS[ct][rt] = __builtin_amdgcn_mfma_f32_16x16x32_bf16(
                        khf[ct], qhf[rt], accS[ct][rt], 0, 0, 0);
                    accS[ct][rt] = __builtin_amdgcn_mfma_f32_16x16x32_bf16(
                        khf[ct], qlf[rt], accS[ct][rt], 0, 0, 0);
                    accS[ct][rt] = __builtin_amdgcn_mfma_f32_16x16x32_bf16(
                        klf[ct], qhf[rt], accS[ct][rt], 0, 0, 0);
                }
        }

        // online softmax (exp2 domain, scale pre-folded); row r owned by lanes with same li
#pragma unroll
        for (int rt = 0; rt < 2; rt++) {
            float mx = -1e30f;
#pragma unroll
            for (int ct = 0; ct < 4; ct++)
#pragma unroll
                for (int rg = 0; rg < 4; rg++) mx = fmaxf(mx, accS[ct][rt][rg]);
            mx = fmaxf(mx, __shfl_xor(mx, 16));
            mx = fmaxf(mx, __shfl_xor(mx, 32));
            float mnew = fmaxf(mrun[rt], mx);
            float alpha = exp2f(mrun[rt] - mnew);
            float ls = 0.f;
            int prow = r0w + rt * 16 + li;
#pragma unroll
            for (int ct = 0; ct < 4; ct++) {
                bf4v pv;
#pragma unroll
                for (int rg = 0; rg < 4; rg++) {
                    float p_ = exp2f(accS[ct][rt][rg] - mnew);
                    ls += p_;
                    pv[rg] = (bf16)p_;
                }
                *(bf4v*)&Pb[prow * 72 + ct * 16 + qq * 4] = pv;
            }
            ls += __shfl_xor(ls, 16);
            ls += __shfl_xor(ls, 32);
            lsum[rt] = lsum[rt] * alpha + ls;
            mrun[rt] = mnew;
#pragma unroll
            for (int dt = 0; dt < 4; dt++)
#pragma unroll
                for (int rg = 0; rg < 4; rg++) accO[dt][rt][rg] *= alpha;
        }
        asm volatile("" ::: "memory");  // keep P ds_writes before PV ds_reads (wave-private rows)

        // PV: accO[dt][rt] = O^T tile [d][r]
#pragma unroll
        for (int ks = 0; ks < 2; ks++) {
            s8v vf[4], pf[2];
#pragma unroll
            for (int dt = 0; dt < 4; dt++) {
                int row = dt * 16 + li;
                int off = row * 64 + (((ks * 4 + qq) ^ (li & 7)) << 3);
                vf[dt] = *(const s8v*)&Vt[off];
            }
#pragma unroll
            for (int rt = 0; rt < 2; rt++) {
                int row = r0w + rt * 16 + li;
                pf[rt] = *(const s8v*)&Pb[row * 72 + ks * 32 + qq * 8];
            }
#pragma unroll
            for (int dt = 0; dt < 4; dt++)
#pragma unroll
                for (int rt = 0; rt < 2; rt++)
                    accO[dt][rt] = __builtin_amdgcn_mfma_f32_16x16x32_bf16(
                        vf[dt], pf[rt], accO[dt][rt], 0, 0, 0);
        }
    }

    // epilogue: normalize; accO holds O^T[d = dt*16+qq*4+rg][r = r0w+rt*16+li] -- already the
    // orientation the reference's reshape quirk needs. Stage fp32 O^T in LDS, store bf16 rows.
    __syncthreads();
#pragma unroll
    for (int rt = 0; rt < 2; rt++) {
        float inv = 1.f / lsum[rt];
        int rr = r0w + rt * 16 + li;
#pragma unroll
        for (int dt = 0; dt < 4; dt++)
#pragma unroll
            for (int rg = 0; rg < 4; rg++)
                Obuf[(dt * 16 + qq * 4 + rg) * 132 + rr] = accO[dt][rt][rg] * inv;
    }
    __syncthreads();
    {
        int d = tid >> 2, c0 = (tid & 3) * 32;
        const float* src = &Obuf[d * 132 + c0];
        bf16* dst = O + ((size_t)blockIdx.z * 1024 + blockIdx.y * 64 + d) * 1024 + l0 + c0;
#pragma unroll
        for (int q8 = 0; q8 < 4; q8++) {
            bf8v o;
#pragma unroll
            for (int j = 0; j < 8; j++) o[j] = (bf16)src[q8 * 8 + j];
            *(bf8v*)&dst[q8 * 8] = o;
        }
    }
}

extern "C" void kernel_launch(void* const* d_in, const int* in_sizes, int n_in,
                              void* d_out, int out_size, void* d_ws, size_t ws_size,
                              hipStream_t stream) {
    const float* queries = (const float*)d_in[0];
    const float* keys    = (const float*)d_in[1];
    const float* values  = (const float*)d_in[2];
    const float* routers = (const float*)d_in[3];
    const float* Wq  = (const float*)d_in[4];
    const float* Wk  = (const float*)d_in[5];
    const float* Wv  = (const float*)d_in[6];
    const float* Wlq = (const float*)d_in[7];
    const float* Wlk = (const float*)d_in[8];
    const float* Wo  = (const float*)d_in[9];
    const float* bo  = (const float*)d_in[10];
    float* out = (float*)d_out;

    // workspace: 6 x 16.78MB big buffers + 14.7MB small = ~115.3 MB (140.5 MB proven in round 1)
    char* w = (char*)d_ws;
    const size_t BIG = 16777216;
    bf16* QwHi = (bf16*)(w);
    bf16* QwLo = (bf16*)(w + 1 * BIG);
    bf16* Thi  = (bf16*)(w + 2 * BIG);   // WqWepT hi -> reused as KpHi
    bf16* Tlo  = (bf16*)(w + 3 * BIG);   // WqWepT lo -> reused as KpLo
    bf16* actHi = (bf16*)(w + 4 * BIG);  // split activations -> reused as attn out Obf
    bf16* actLo = (bf16*)(w + 5 * BIG);  // split activations -> reused as VT
    char* w2 = w + 6 * BIG;
    const size_t SM = 2097152;
    bf16*  WkThi = (bf16*)(w2);
    bf16*  WkTlo = (bf16*)(w2 + 1 * SM);
    bf16*  WvT   = (bf16*)(w2 + 2 * SM);
    bf16*  WoT   = (bf16*)(w2 + 3 * SM);
    float* RQ    = (float*)(w2 + 4 * SM);
    float* RK    = (float*)(w2 + 5 * SM);
    float* WEP   = (float*)(w2 + 6 * SM);
    bf16* KpHi = Thi;
    bf16* KpLo = Tlo;
    bf16* VTp  = actLo;
    bf16* Obf  = actHi;

    dim3 blk(256);
    // weight prep
    transw_k<<<dim3(16, 16), blk, 0, stream>>>(Wk, WkThi, WkTlo);
    transw_k<<<dim3(16, 16), blk, 0, stream>>>(Wv, WvT, nullptr);
    transw_k<<<dim3(16, 16), blk, 0, stream>>>(Wo, WoT, nullptr);
    // router path (fp32 exact)
    sgemm_k<<<dim3(4, 8), blk, 0, stream>>>(routers, Wlq, RQ, 1, nullptr, 64);
    sgemm_k<<<dim3(4, 8), blk, 0, stream>>>(routers, Wlk, RK, 1, nullptr, 64);
    wep_k<<<dim3(BB * NH), blk, 0, stream>>>(RQ, RK, WEP);
    wqwep_k<<<dim3(BB * NH), blk, 0, stream>>>(Wq, WEP, Thi, Tlo);
    // Qw = queries @ (Wq Wep)[b], 3-pass split x split, split-headed out
    split_cast_k<<<1024, blk, 0, stream>>>(queries, actHi, actLo, 2097152);
    gemm_k<3><<<dim3(64, 8), blk, 0, stream>>>(actHi, actLo, Thi, Tlo, 1, 1,
                                               nullptr, nullptr, QwHi, QwLo);
    // Kp = keys @ Wk, 3-pass split x split, split-headed out (overwrites Thi/Tlo)
    split_cast_k<<<1024, blk, 0, stream>>>(keys, actHi, actLo, 2097152);
    gemm_k<3><<<dim3(64, 8), blk, 0, stream>>>(actHi, actLo, WkThi, WkTlo, 0, 1,
                                               nullptr, nullptr, KpHi, KpLo);
    // V^T = (values @ Wv)^T, plain bf16 (error negligible on V path)
    split_cast_k<<<1024, blk, 0, stream>>>(values, actHi, nullptr, 2097152);
    gemm_k<1><<<dim3(64, 8), blk, 0, stream>>>(actHi, nullptr, WvT, nullptr, 0, 2,
                                               nullptr, nullptr, VTp, nullptr);
    // fused attention -> O^T quirk layout [b][h*64+d][l]
    attn_k<<<dim3(8, NH, BB), blk, 0, stream>>>(QwHi, QwLo, KpHi, KpLo, VTp, Obf);
    // out = Obf @ Wo + bo (fp32 out)
    gemm_k<1><<<dim3(64, 8), blk, 0, stream>>>(Obf, nullptr, WoT, nullptr, 0, 0,
                                               out, bo, nullptr, nullptr);
}

// Round 4
// 638.940 us; speedup vs baseline: 4.0424x; 1.2951x over previous
//
#include <hip/hip_runtime.h>

typedef __bf16 bf16;
typedef short s8v __attribute__((ext_vector_type(8)));    // 8 bf16 as shorts (4 VGPR) - MFMA A/B frag
typedef float f4v __attribute__((ext_vector_type(4)));    // MFMA C/D frag
typedef bf16 bf4v __attribute__((ext_vector_type(4)));
typedef bf16 bf8v __attribute__((ext_vector_type(8)));

#define NH 16
#define BB 8
#define QWSCALE 0.18033688011112043f  /* 0.125 * log2(e): scores in exp2 domain */

__device__ __forceinline__ void glds16(void* lds, const void* g) {
    __builtin_amdgcn_global_load_lds(
        (const __attribute__((address_space(1))) unsigned int*)g,
        (__attribute__((address_space(3))) unsigned int*)lds, 16, 0, 0);
}

// ------ fused router GEMM: C1=A@W1, C2=A@W2; M=512, N=K=1024; 64x64 tiles, 256 blocks ------
// headed out: m=b*64+g (Lrows=64), n=h*64+d -> C[((b*16+h)*64+g)*64+d]
__global__ __launch_bounds__(256) void rgemm_k(
    const float* __restrict__ A, const float* __restrict__ W1, const float* __restrict__ W2,
    float* __restrict__ C1, float* __restrict__ C2)
{
    __shared__ float As[16][68];   // [k][m]
    __shared__ float Bs[16][68];   // [k][n]
    const int tid = threadIdx.x;
    const int bm = blockIdx.x;           // 0..7  (= batch b)
    int bn = blockIdx.y;                 // 0..31
    const float* W = (bn < 16) ? W1 : W2;
    float* C = (bn < 16) ? C1 : C2;
    if (bn >= 16) bn -= 16;              // head h = bn
    const int n0 = bn * 64;

    const int ar = tid >> 2, ac = (tid & 3) * 4;     // A loader: row, k-quad
    const int br = tid >> 4, bc = (tid & 15) * 4;    // B loader: k-row, n-quad
    const int tr = (tid >> 4) * 4, tc = (tid & 15) * 4;

    float acc[4][4];
#pragma unroll
    for (int i = 0; i < 4; i++)
#pragma unroll
        for (int j = 0; j < 4; j++) acc[i][j] = 0.f;

    for (int kt = 0; kt < 1024; kt += 16) {
        float4 av = *(const float4*)&A[(size_t)(bm * 64 + ar) * 1024 + kt + ac];
        float4 bv = *(const float4*)&W[(size_t)(kt + br) * 1024 + n0 + bc];
        __syncthreads();
        As[ac + 0][ar] = av.x; As[ac + 1][ar] = av.y;
        As[ac + 2][ar] = av.z; As[ac + 3][ar] = av.w;
        *(float4*)&Bs[br][bc] = bv;
        __syncthreads();
#pragma unroll
        for (int k = 0; k < 16; k++) {
            float4 x = *(const float4*)&As[k][tr];
            float4 y = *(const float4*)&Bs[k][tc];
            float xv[4] = {x.x, x.y, x.z, x.w};
            float yv[4] = {y.x, y.y, y.z, y.w};
#pragma unroll
            for (int i = 0; i < 4; i++)
#pragma unroll
                for (int j = 0; j < 4; j++) acc[i][j] += xv[i] * yv[j];
        }
    }

#pragma unroll
    for (int i = 0; i < 4; i++) {
        float4 v = make_float4(acc[i][0], acc[i][1], acc[i][2], acc[i][3]);
        *(float4*)&C[((size_t)(bm * NH + bn) * 64 + tr + i) * 64 + tc] = v;
    }
}

// ---------------- W_ep[b,h][d][e] = sum_g rq[g][d] * rk[g][e]  (fp32) ----------------
__global__ __launch_bounds__(256) void wep_k(
    const float* __restrict__ RQ, const float* __restrict__ RK, float* __restrict__ WEP)
{
    const int bh = blockIdx.x;
    __shared__ float rqs[4096];
    __shared__ float rks[4096];
    const int tid = threadIdx.x;
    const float4* rq4 = (const float4*)(RQ + (size_t)bh * 4096);
    const float4* rk4 = (const float4*)(RK + (size_t)bh * 4096);
#pragma unroll
    for (int j = 0; j < 4; j++) {
        ((float4*)rqs)[tid + 256 * j] = rq4[tid + 256 * j];
        ((float4*)rks)[tid + 256 * j] = rk4[tid + 256 * j];
    }
    __syncthreads();
    const int dd = tid >> 2, q = (tid & 3) * 16;
    float acc[16];
#pragma unroll
    for (int i = 0; i < 16; i++) acc[i] = 0.f;
    for (int g = 0; g < 64; g++) {
        float a = rqs[g * 64 + dd];
#pragma unroll
        for (int i = 0; i < 16; i++) acc[i] += a * rks[g * 64 + q + i];
    }
    float* out = WEP + (size_t)bh * 4096 + dd * 64 + q;
#pragma unroll
    for (int i4 = 0; i4 < 4; i4++)
        *(float4*)&out[i4 * 4] =
            make_float4(acc[i4 * 4], acc[i4 * 4 + 1], acc[i4 * 4 + 2], acc[i4 * 4 + 3]);
}

// -------- WqWepT hi/lo [b][n=h*64+e][k=D] = scale * sum_d Wep[b,h][d][e] * Wq[D][h*64+d] --------
__global__ __launch_bounds__(256) void wqwep_k(
    const float* __restrict__ Wq, const float* __restrict__ WEP,
    bf16* __restrict__ Thi, bf16* __restrict__ Tlo)
{
    const int b = blockIdx.x >> 4, h = blockIdx.x & 15;
    __shared__ float weps[4096];       // [d][e]
    __shared__ float wqs[128 * 68];    // [Dloc][d]
    const int tid = threadIdx.x;
    const float4* wsrc = (const float4*)(WEP + (size_t)blockIdx.x * 4096);
#pragma unroll
    for (int it = 0; it < 4; it++)
        ((float4*)weps)[it * 256 + tid] = wsrc[it * 256 + tid];
    const int Dloc = tid >> 1, e0 = (tid & 1) * 32;
    for (int Dt = 0; Dt < 8; Dt++) {
        __syncthreads();
#pragma unroll
        for (int it = 0; it < 8; it++) {
            int g = it * 256 + tid;
            int r = g >> 4, c = (g & 15) * 4;
            *(float4*)&wqs[r * 68 + c] =
                *(const float4*)&Wq[(size_t)(Dt * 128 + r) * 1024 + h * 64 + c];
        }
        __syncthreads();
        float acc[32];
#pragma unroll
        for (int e = 0; e < 32; e++) acc[e] = 0.f;
        for (int d = 0; d < 64; d++) {
            float a = wqs[Dloc * 68 + d];
            const float* wr = &weps[d * 64 + e0];
#pragma unroll
            for (int e = 0; e < 32; e++) acc[e] += a * wr[e];
        }
        int D = Dt * 128 + Dloc;
        size_t row0 = (size_t)b * 1024 + h * 64 + e0;
#pragma unroll
        for (int e = 0; e < 32; e++) {
            float v = acc[e] * QWSCALE;
            bf16 hv = (bf16)v;
            Thi[(row0 + e) * 1024 + D] = hv;
            Tlo[(row0 + e) * 1024 + D] = (bf16)(v - (float)hv);
        }
    }
}

// ---------------- split/cast fp32 -> bf16 hi (+lo) ----------------
__global__ void split_cast_k(const float* __restrict__ x, bf16* __restrict__ hi,
                             bf16* __restrict__ lo, int n4)
{
    int idx = blockIdx.x * blockDim.x + threadIdx.x;
    int stride = gridDim.x * blockDim.x;
    for (int i = idx; i < n4; i += stride) {
        float4 v = ((const float4*)x)[i];
        bf4v h;
        h[0] = (bf16)v.x; h[1] = (bf16)v.y; h[2] = (bf16)v.z; h[3] = (bf16)v.w;
        ((bf4v*)hi)[i] = h;
        if (lo) {
            bf4v l;
            l[0] = (bf16)(v.x - (float)h[0]);
            l[1] = (bf16)(v.y - (float)h[1]);
            l[2] = (bf16)(v.z - (float)h[2]);
            l[3] = (bf16)(v.w - (float)h[3]);
            ((bf4v*)lo)[i] = l;
        }
    }
}

// ------- transpose fp32 W[k][n] -> bf16 WT[n][k] (1024x1024), optional hi/lo split -------
__global__ __launch_bounds__(256) void transw_k(const float* __restrict__ W,
                                                bf16* __restrict__ WT, bf16* __restrict__ WTlo)
{
    __shared__ float T[64 * 68];
    const int k0 = blockIdx.x * 64, n0 = blockIdx.y * 64;
    const int tid = threadIdx.x;
#pragma unroll
    for (int it = 0; it < 4; it++) {
        int g = it * 256 + tid;
        int r = g >> 4, c = (g & 15) * 4;
        *(float4*)&T[r * 68 + c] = *(const float4*)&W[(size_t)(k0 + r) * 1024 + n0 + c];
    }
    __syncthreads();
#pragma unroll
    for (int it = 0; it < 4; it++) {
        int g = it * 256 + tid;
        int n = g >> 4, k4 = (g & 15) * 4;
        bf4v o, ol;
#pragma unroll
        for (int t = 0; t < 4; t++) {
            float v = T[(k4 + t) * 68 + n];
            o[t] = (bf16)v;
            ol[t] = (bf16)(v - (float)o[t]);
        }
        *(bf4v*)&WT[(size_t)(n0 + n) * 1024 + k0 + k4] = o;
        if (WTlo) *(bf4v*)&WTlo[(size_t)(n0 + n) * 1024 + k0 + k4] = ol;
    }
}

// ---------------- bf16 MFMA GEMM: C[m][n] = A[m][k] @ Bt[n][k]^T, M=8192, N=K=1024 ----------------
// PASSES=3: A and B both hi/lo split: acc = AhiBhi + AloBhi + AhiBlo (drop lo*lo).
// outmode 0: fp32 out[m*1024+n] + bias[n]
// outmode 1: split-headed bf16: outH/outL[((b*16+h)*1024+l)*64+e]
// outmode 2: VT bf16: outH[((b*16+h)*64+d)*1024+s]
template<int PASSES>
__global__ __launch_bounds__(256, 2) void gemm_k(
    const bf16* __restrict__ A, const bf16* __restrict__ Alo,
    const bf16* __restrict__ Bt, const bf16* __restrict__ Btlo,
    int bBatched, int outmode,
    float* __restrict__ outF, const float* __restrict__ bias,
    bf16* __restrict__ outH, bf16* __restrict__ outL)
{
    __shared__ bf16 Ah[128 * 64];
    __shared__ bf16 Bh[128 * 64];
    __shared__ bf16 Al[(PASSES == 3) ? 128 * 64 : 64];
    __shared__ bf16 Bl[(PASSES == 3) ? 128 * 64 : 64];
    const int tid = threadIdx.x;
    const int bm = blockIdx.x, bn = blockIdx.y;
    const size_t boff = bBatched ? ((size_t)(bm >> 3) << 20) : (size_t)0;
    const bf16* Bt_b = Bt + boff;
    const bf16* Btlo_b = (PASSES == 3) ? (Btlo + boff) : nullptr;
    const int li = tid & 15;
    const int qq = (tid >> 4) & 3;
    const int wave = tid >> 6;
    const int wm0 = (wave & 1) * 64, wn0 = (wave >> 1) * 64;

    f4v acc[4][4];
    f4v zf; zf[0] = 0.f; zf[1] = 0.f; zf[2] = 0.f; zf[3] = 0.f;
#pragma unroll
    for (int mt = 0; mt < 4; mt++)
#pragma unroll
        for (int nt = 0; nt < 4; nt++) acc[mt][nt] = zf;

    for (int kt = 0; kt < 16; kt++) {
        const int col0 = kt * 64;
#pragma unroll
        for (int it = 0; it < 4; it++) {
            int g = it * 256 + tid;
            int r = g >> 3, p = g & 7;
            int gcol = col0 + ((p ^ (r & 7)) << 3);
            int ldsoff = (g & ~63) << 3;
            size_t ga = (size_t)(bm * 128 + r) * 1024 + gcol;
            size_t gb = (size_t)(bn * 128 + r) * 1024 + gcol;
            glds16(Ah + ldsoff, A + ga);
            glds16(Bh + ldsoff, Bt_b + gb);
            if (PASSES == 3) {
                glds16(Al + ldsoff, Alo + ga);
                glds16(Bl + ldsoff, Btlo_b + gb);
            }
        }
        __syncthreads();
#pragma unroll
        for (int ks = 0; ks < 2; ks++) {
            s8v af[4], alf[4], bhf[4], blf[4];
#pragma unroll
            for (int mt = 0; mt < 4; mt++) {
                int row = wm0 + mt * 16 + li;
                int off = row * 64 + (((ks * 4 + qq) ^ (li & 7)) << 3);
                af[mt] = *(const s8v*)&Ah[off];
                if (PASSES == 3) alf[mt] = *(const s8v*)&Al[off];
            }
#pragma unroll
            for (int nt = 0; nt < 4; nt++) {
                int row = wn0 + nt * 16 + li;
                int off = row * 64 + (((ks * 4 + qq) ^ (li & 7)) << 3);
                bhf[nt] = *(const s8v*)&Bh[off];
                if (PASSES == 3) blf[nt] = *(const s8v*)&Bl[off];
            }
#pragma unroll
            for (int mt = 0; mt < 4; mt++)
#pragma unroll
                for (int nt = 0; nt < 4; nt++) {
                    acc[mt][nt] = __builtin_amdgcn_mfma_f32_16x16x32_bf16(
                        af[mt], bhf[nt], acc[mt][nt], 0, 0, 0);
                    if (PASSES == 3) {
                        acc[mt][nt] = __builtin_amdgcn_mfma_f32_16x16x32_bf16(
                            alf[mt], bhf[nt], acc[mt][nt], 0, 0, 0);
                        acc[mt][nt] = __builtin_amdgcn_mfma_f32_16x16x32_bf16(
                            af[mt], blf[nt], acc[mt][nt], 0, 0, 0);
                    }
                }
        }
        __syncthreads();
    }

    // epilogue
#pragma unroll
    for (int mt = 0; mt < 4; mt++) {
#pragma unroll
        for (int nt = 0; nt < 4; nt++) {
            int n = bn * 128 + wn0 + nt * 16 + li;
            int m0 = bm * 128 + wm0 + mt * 16 + qq * 4;
            if (outmode == 0) {
                float bv = bias[n];
#pragma unroll
                for (int rg = 0; rg < 4; rg++)
                    outF[(size_t)(m0 + rg) * 1024 + n] = acc[mt][nt][rg] + bv;
            } else if (outmode == 1) {
                int h = n >> 6, e = n & 63;
#pragma unroll
                for (int rg = 0; rg < 4; rg++) {
                    int m = m0 + rg;
                    int b = m >> 10, l = m & 1023;
                    size_t idx = ((size_t)(b * NH + h) * 1024 + l) * 64 + e;
                    float v = acc[mt][nt][rg];
                    bf16 hv = (bf16)v;
                    outH[idx] = hv;
                    outL[idx] = (bf16)(v - (float)hv);
                }
            } else {
                int b = m0 >> 10, s = m0 & 1023;
                int h = n >> 6, d = n & 63;
                bf4v v;
                v[0] = (bf16)acc[mt][nt][0]; v[1] = (bf16)acc[mt][nt][1];
                v[2] = (bf16)acc[mt][nt][2]; v[3] = (bf16)acc[mt][nt][3];
                *(bf4v*)&outH[((size_t)(b * NH + h) * 64 + d) * 1024 + s] = v;
            }
        }
    }
}

// ---------------- fused attention: S^T = Kp·Qw^T 3-pass, online softmax, O^T = V^T·P^T ----------------
// Output layout honors the reference's reshape quirk: O[b][h*64+d][l]  (K-dim of final GEMM = l)
__global__ __launch_bounds__(256, 2) void attn_k(
    const bf16* __restrict__ QwHi, const bf16* __restrict__ QwLo,
    const bf16* __restrict__ KpHi, const bf16* __restrict__ KpLo,
    const bf16* __restrict__ VT, bf16* __restrict__ O)
{
    __shared__ bf16 Qh[128 * 64];
    __shared__ bf16 Ql[128 * 64];
    __shared__ __align__(16) char scratch[43008];
    bf16* Kh = (bf16*)scratch;          // [64][64]
    bf16* Kl = Kh + 4096;               // [64][64]
    bf16* Vt = Kh + 8192;               // [64 d][64 s]
    bf16* Pb = Kh + 12288;              // [128 r][stride 72]
    float* Obuf = (float*)scratch;      // [64 d][stride 132] (epilogue reuse)

    const int tid = threadIdx.x;
    const int l0 = blockIdx.x * 128;
    const int bh = blockIdx.z * NH + blockIdx.y;
    const int li = tid & 15;
    const int qq = (tid >> 4) & 3;
    const int wave = tid >> 6;
    const int r0w = wave * 32;

    // prologue: stage Qw hi/lo tile [128 l][64 e] (xor-swizzled)
    const bf16* qhsrc = QwHi + ((size_t)bh * 1024 + l0) * 64;
    const bf16* qlsrc = QwLo + ((size_t)bh * 1024 + l0) * 64;
#pragma unroll
    for (int it = 0; it < 8; it++) {
        int g = it * 256 + tid;
        int buf = g >> 10;
        int L = g & 1023;
        int r = L >> 3, p = L & 7;
        int goff = r * 64 + ((p ^ (r & 7)) << 3);
        glds16((buf ? Ql : Qh) + ((L & ~63) << 3), (buf ? qlsrc : qhsrc) + goff);
    }

    float mrun[2], lsum[2];
    mrun[0] = -__builtin_inff(); mrun[1] = -__builtin_inff();
    lsum[0] = 0.f; lsum[1] = 0.f;
    f4v accO[4][2];
    {
        f4v zf; zf[0] = 0.f; zf[1] = 0.f; zf[2] = 0.f; zf[3] = 0.f;
#pragma unroll
        for (int dt = 0; dt < 4; dt++) { accO[dt][0] = zf; accO[dt][1] = zf; }
    }

    for (int s0 = 0; s0 < 1024; s0 += 64) {
        __syncthreads();  // previous chunk's K/V/P reads done (also drains prologue loads)
#pragma unroll
        for (int it = 0; it < 6; it++) {
            int g = it * 256 + tid;
            int buf = g >> 9;
            int L = g & 511;
            int r = L >> 3, p = L & 7;
            int blk = (p ^ (r & 7)) << 3;
            const bf16* src;
            bf16* dstb;
            if (buf == 0)      { src = KpHi + ((size_t)bh * 1024 + s0 + r) * 64 + blk; dstb = Kh; }
            else if (buf == 1) { src = KpLo + ((size_t)bh * 1024 + s0 + r) * 64 + blk; dstb = Kl; }
            else               { src = VT + ((size_t)bh * 64 + r) * 1024 + s0 + blk;   dstb = Vt; }
            glds16(dstb + ((L & ~63) << 3), src);
        }
        __syncthreads();

        // scores: accS[ct][rt] = S^T tile; S^T rows c = ct*16+qq*4+rg, cols r = r0w+rt*16+li
        f4v accS[4][2];
        {
            f4v zf; zf[0] = 0.f; zf[1] = 0.f; zf[2] = 0.f; zf[3] = 0.f;
#pragma unroll
            for (int ct = 0; ct < 4; ct++) { accS[ct][0] = zf; accS[ct][1] = zf; }
        }
#pragma unroll
        for (int ks = 0; ks < 2; ks++) {
            s8v khf[4], klf[4], qhf[2], qlf[2];
#pragma unroll
            for (int ct = 0; ct < 4; ct++) {
                int row = ct * 16 + li;
                int off = row * 64 + (((ks * 4 + qq) ^ (li & 7)) << 3);
                khf[ct] = *(const s8v*)&Kh[off];
                klf[ct] = *(const s8v*)&Kl[off];
            }
#pragma unroll
            for (int rt = 0; rt < 2; rt++) {
                int row = r0w + rt * 16 + li;
                int off = row * 64 + (((ks * 4 + qq) ^ (li & 7)) << 3);
                qhf[rt] = *(const s8v*)&Qh[off];
                qlf[rt] = *(const s8v*)&Ql[off];
            }
#pragma unroll
            for (int ct = 0; ct < 4; ct++)
#pragma unroll
                for (int rt = 0; rt < 2; rt++) {
                    accS[ct][rt] = __builtin_amdgcn_mfma_f32_16x16x32_bf16(
                        khf[ct], qhf[rt], accS[ct][rt], 0, 0, 0);
                    accS[ct][rt] = __builtin_amdgcn_mfma_f32_16x16x32_bf16(
                        khf[ct], qlf[rt], accS[ct][rt], 0, 0, 0);
                    accS[ct][rt] = __builtin_amdgcn_mfma_f32_16x16x32_bf16(
                        klf[ct], qhf[rt], accS[ct][rt], 0, 0, 0);
                }
        }

        // online softmax (exp2 domain, scale pre-folded); row r owned by lanes with same li
#pragma unroll
        for (int rt = 0; rt < 2; rt++) {
            float mx = -1e30f;
#pragma unroll
            for (int ct = 0; ct < 4; ct++)
#pragma unroll
                for (int rg = 0; rg < 4; rg++) mx = fmaxf(mx, accS[ct][rt][rg]);
            mx = fmaxf(mx, __shfl_xor(mx, 16));
            mx = fmaxf(mx, __shfl_xor(mx, 32));
            float mnew = fmaxf(mrun[rt], mx);
            float alpha = exp2f(mrun[rt] - mnew);
            float ls = 0.f;
            int prow = r0w + rt * 16 + li;
#pragma unroll
            for (int ct = 0; ct < 4; ct++) {
                bf4v pv;
#pragma unroll
                for (int rg = 0; rg < 4; rg++) {
                    float p_ = exp2f(accS[ct][rt][rg] - mnew);
                    ls += p_;
                    pv[rg] = (bf16)p_;
                }
                *(bf4v*)&Pb[prow * 72 + ct * 16 + qq * 4] = pv;
            }
            ls += __shfl_xor(ls, 16);
            ls += __shfl_xor(ls, 32);
            lsum[rt] = lsum[rt] * alpha + ls;
            mrun[rt] = mnew;
#pragma unroll
            for (int dt = 0; dt < 4; dt++)
#pragma unroll
                for (int rg = 0; rg < 4; rg++) accO[dt][rt][rg] *= alpha;
        }
        asm volatile("" ::: "memory");  // keep P ds_writes before PV ds_reads (wave-private rows)

        // PV: accO[dt][rt] = O^T tile [d][r]
#pragma unroll
        for (int ks = 0; ks < 2; ks++) {
            s8v vf[4], pf[2];
#pragma unroll
            for (int dt = 0; dt < 4; dt++) {
                int row = dt * 16 + li;
                int off = row * 64 + (((ks * 4 + qq) ^ (li & 7)) << 3);
                vf[dt] = *(const s8v*)&Vt[off];
            }
#pragma unroll
            for (int rt = 0; rt < 2; rt++) {
                int row = r0w + rt * 16 + li;
                pf[rt] = *(const s8v*)&Pb[row * 72 + ks * 32 + qq * 8];
            }
#pragma unroll
            for (int dt = 0; dt < 4; dt++)
#pragma unroll
                for (int rt = 0; rt < 2; rt++)
                    accO[dt][rt] = __builtin_amdgcn_mfma_f32_16x16x32_bf16(
                        vf[dt], pf[rt], accO[dt][rt], 0, 0, 0);
        }
    }

    // epilogue: normalize; accO holds O^T[d = dt*16+qq*4+rg][r = r0w+rt*16+li] -- already the
    // orientation the reference's reshape quirk needs. Stage fp32 O^T in LDS, store bf16 rows.
    __syncthreads();
#pragma unroll
    for (int rt = 0; rt < 2; rt++) {
        float inv = 1.f / lsum[rt];
        int rr = r0w + rt * 16 + li;
#pragma unroll
        for (int dt = 0; dt < 4; dt++)
#pragma unroll
            for (int rg = 0; rg < 4; rg++)
                Obuf[(dt * 16 + qq * 4 + rg) * 132 + rr] = accO[dt][rt][rg] * inv;
    }
    __syncthreads();
    {
        int d = tid >> 2, c0 = (tid & 3) * 32;
        const float* src = &Obuf[d * 132 + c0];
        bf16* dst = O + ((size_t)blockIdx.z * 1024 + blockIdx.y * 64 + d) * 1024 + l0 + c0;
#pragma unroll
        for (int q8 = 0; q8 < 4; q8++) {
            bf8v o;
#pragma unroll
            for (int j = 0; j < 8; j++) o[j] = (bf16)src[q8 * 8 + j];
            *(bf8v*)&dst[q8 * 8] = o;
        }
    }
}

extern "C" void kernel_launch(void* const* d_in, const int* in_sizes, int n_in,
                              void* d_out, int out_size, void* d_ws, size_t ws_size,
                              hipStream_t stream) {
    const float* queries = (const float*)d_in[0];
    const float* keys    = (const float*)d_in[1];
    const float* values  = (const float*)d_in[2];
    const float* routers = (const float*)d_in[3];
    const float* Wq  = (const float*)d_in[4];
    const float* Wk  = (const float*)d_in[5];
    const float* Wv  = (const float*)d_in[6];
    const float* Wlq = (const float*)d_in[7];
    const float* Wlk = (const float*)d_in[8];
    const float* Wo  = (const float*)d_in[9];
    const float* bo  = (const float*)d_in[10];
    float* out = (float*)d_out;

    // workspace: 6 x 16.78MB big buffers + 14.7MB small = ~115.3 MB (140.5 MB proven in round 1)
    char* w = (char*)d_ws;
    const size_t BIG = 16777216;
    bf16* QwHi = (bf16*)(w);
    bf16* QwLo = (bf16*)(w + 1 * BIG);
    bf16* Thi  = (bf16*)(w + 2 * BIG);   // WqWepT hi -> reused as KpHi
    bf16* Tlo  = (bf16*)(w + 3 * BIG);   // WqWepT lo -> reused as KpLo
    bf16* actHi = (bf16*)(w + 4 * BIG);  // split activations -> reused as attn out Obf
    bf16* actLo = (bf16*)(w + 5 * BIG);  // split activations -> reused as VT
    char* w2 = w + 6 * BIG;
    const size_t SM = 2097152;
    bf16*  WkThi = (bf16*)(w2);
    bf16*  WkTlo = (bf16*)(w2 + 1 * SM);
    bf16*  WvT   = (bf16*)(w2 + 2 * SM);
    bf16*  WoT   = (bf16*)(w2 + 3 * SM);
    float* RQ    = (float*)(w2 + 4 * SM);
    float* RK    = (float*)(w2 + 5 * SM);
    float* WEP   = (float*)(w2 + 6 * SM);
    bf16* KpHi = Thi;
    bf16* KpLo = Tlo;
    bf16* VTp  = actLo;
    bf16* Obf  = actHi;

    dim3 blk(256);
    // weight prep
    transw_k<<<dim3(16, 16), blk, 0, stream>>>(Wk, WkThi, WkTlo);
    transw_k<<<dim3(16, 16), blk, 0, stream>>>(Wv, WvT, nullptr);
    transw_k<<<dim3(16, 16), blk, 0, stream>>>(Wo, WoT, nullptr);
    // router path (fp32 exact): both projections in one 256-block launch
    rgemm_k<<<dim3(8, 32), blk, 0, stream>>>(routers, Wlq, Wlk, RQ, RK);
    wep_k<<<dim3(BB * NH), blk, 0, stream>>>(RQ, RK, WEP);
    wqwep_k<<<dim3(BB * NH), blk, 0, stream>>>(Wq, WEP, Thi, Tlo);
    // Qw = queries @ (Wq Wep)[b], 3-pass split x split, split-headed out
    split_cast_k<<<1024, blk, 0, stream>>>(queries, actHi, actLo, 2097152);
    gemm_k<3><<<dim3(64, 8), blk, 0, stream>>>(actHi, actLo, Thi, Tlo, 1, 1,
                                               nullptr, nullptr, QwHi, QwLo);
    // Kp = keys @ Wk, 3-pass split x split, split-headed out (overwrites Thi/Tlo)
    split_cast_k<<<1024, blk, 0, stream>>>(keys, actHi, actLo, 2097152);
    gemm_k<3><<<dim3(64, 8), blk, 0, stream>>>(actHi, actLo, WkThi, WkTlo, 0, 1,
                                               nullptr, nullptr, KpHi, KpLo);
    // V^T = (values @ Wv)^T, plain bf16 (error negligible on V path)
    split_cast_k<<<1024, blk, 0, stream>>>(values, actHi, nullptr, 2097152);
    gemm_k<1><<<dim3(64, 8), blk, 0, stream>>>(actHi, nullptr, WvT, nullptr, 0, 2,
                                               nullptr, nullptr, VTp, nullptr);
    // fused attention -> O^T quirk layout [b][h*64+d][l]
    attn_k<<<dim3(8, NH, BB), blk, 0, stream>>>(QwHi, QwLo, KpHi, KpLo, VTp, Obf);
    // out = Obf @ Wo + bo (fp32 out)
    gemm_k<1><<<dim3(64, 8), blk, 0, stream>>>(Obf, nullptr, WoT, nullptr, 0, 0,
                                               out, bo, nullptr, nullptr);
}

// Round 5
// 553.271 us; speedup vs baseline: 4.6684x; 1.1548x over previous
//
#include <hip/hip_runtime.h>

typedef __bf16 bf16;
typedef short s8v __attribute__((ext_vector_type(8)));    // 8 bf16 as shorts (4 VGPR) - MFMA A/B frag
typedef float f4v __attribute__((ext_vector_type(4)));    // MFMA C/D frag
typedef bf16 bf4v __attribute__((ext_vector_type(4)));
typedef bf16 bf8v __attribute__((ext_vector_type(8)));

#define NH 16
#define BB 8
#define QWSCALE 0.18033688011112043f  /* 0.125 * log2(e): scores in exp2 domain */

__device__ __forceinline__ void glds16(void* lds, const void* g) {
    __builtin_amdgcn_global_load_lds(
        (const __attribute__((address_space(1))) unsigned int*)g,
        (__attribute__((address_space(3))) unsigned int*)lds, 16, 0, 0);
}

// ------ fused router GEMM: C1=A@W1, C2=A@W2; M=512, N=K=1024; 64x64 tiles, 256 blocks ------
// headed out: m=b*64+g (Lrows=64), n=h*64+d -> C[((b*16+h)*64+g)*64+d]
__global__ __launch_bounds__(256) void rgemm_k(
    const float* __restrict__ A, const float* __restrict__ W1, const float* __restrict__ W2,
    float* __restrict__ C1, float* __restrict__ C2)
{
    __shared__ float As[16][68];   // [k][m]
    __shared__ float Bs[16][68];   // [k][n]
    const int tid = threadIdx.x;
    const int bm = blockIdx.x;           // 0..7  (= batch b)
    int bn = blockIdx.y;                 // 0..31
    const float* W = (bn < 16) ? W1 : W2;
    float* C = (bn < 16) ? C1 : C2;
    if (bn >= 16) bn -= 16;              // head h = bn
    const int n0 = bn * 64;

    const int ar = tid >> 2, ac = (tid & 3) * 4;     // A loader: row, k-quad
    const int br = tid >> 4, bc = (tid & 15) * 4;    // B loader: k-row, n-quad
    const int tr = (tid >> 4) * 4, tc = (tid & 15) * 4;

    float acc[4][4];
#pragma unroll
    for (int i = 0; i < 4; i++)
#pragma unroll
        for (int j = 0; j < 4; j++) acc[i][j] = 0.f;

    for (int kt = 0; kt < 1024; kt += 16) {
        float4 av = *(const float4*)&A[(size_t)(bm * 64 + ar) * 1024 + kt + ac];
        float4 bv = *(const float4*)&W[(size_t)(kt + br) * 1024 + n0 + bc];
        __syncthreads();
        As[ac + 0][ar] = av.x; As[ac + 1][ar] = av.y;
        As[ac + 2][ar] = av.z; As[ac + 3][ar] = av.w;
        *(float4*)&Bs[br][bc] = bv;
        __syncthreads();
#pragma unroll
        for (int k = 0; k < 16; k++) {
            float4 x = *(const float4*)&As[k][tr];
            float4 y = *(const float4*)&Bs[k][tc];
            float xv[4] = {x.x, x.y, x.z, x.w};
            float yv[4] = {y.x, y.y, y.z, y.w};
#pragma unroll
            for (int i = 0; i < 4; i++)
#pragma unroll
                for (int j = 0; j < 4; j++) acc[i][j] += xv[i] * yv[j];
        }
    }

#pragma unroll
    for (int i = 0; i < 4; i++) {
        float4 v = make_float4(acc[i][0], acc[i][1], acc[i][2], acc[i][3]);
        *(float4*)&C[((size_t)(bm * NH + bn) * 64 + tr + i) * 64 + tc] = v;
    }
}

// ---------------- W_ep[b,h][d][e] = sum_g rq[g][d] * rk[g][e]  (fp32) ----------------
__global__ __launch_bounds__(256) void wep_k(
    const float* __restrict__ RQ, const float* __restrict__ RK, float* __restrict__ WEP)
{
    const int bh = blockIdx.x;
    __shared__ float rqs[4096];
    __shared__ float rks[4096];
    const int tid = threadIdx.x;
    const float4* rq4 = (const float4*)(RQ + (size_t)bh * 4096);
    const float4* rk4 = (const float4*)(RK + (size_t)bh * 4096);
#pragma unroll
    for (int j = 0; j < 4; j++) {
        ((float4*)rqs)[tid + 256 * j] = rq4[tid + 256 * j];
        ((float4*)rks)[tid + 256 * j] = rk4[tid + 256 * j];
    }
    __syncthreads();
    const int dd = tid >> 2, q = (tid & 3) * 16;
    float acc[16];
#pragma unroll
    for (int i = 0; i < 16; i++) acc[i] = 0.f;
    for (int g = 0; g < 64; g++) {
        float a = rqs[g * 64 + dd];
#pragma unroll
        for (int i = 0; i < 16; i++) acc[i] += a * rks[g * 64 + q + i];
    }
    float* out = WEP + (size_t)bh * 4096 + dd * 64 + q;
#pragma unroll
    for (int i4 = 0; i4 < 4; i4++)
        *(float4*)&out[i4 * 4] =
            make_float4(acc[i4 * 4], acc[i4 * 4 + 1], acc[i4 * 4 + 2], acc[i4 * 4 + 3]);
}

// -------- WqWepT hi/lo [b][n=h*64+e][k=D] = scale * sum_d Wep[b,h][d][e] * Wq[D][h*64+d] --------
// grid (128 bh, 8 Dt): Dt-loop parallelized across blocks; coalesced stores via LDS pack.
__global__ __launch_bounds__(256) void wqwep_k(
    const float* __restrict__ Wq, const float* __restrict__ WEP,
    bf16* __restrict__ Thi, bf16* __restrict__ Tlo)
{
    const int bh = blockIdx.x;
    const int b = bh >> 4, h = bh & 15;
    const int Dt = blockIdx.y;
    __shared__ float weps[4096];       // [d][e]
    __shared__ float wqs[128 * 68];    // [Dloc][d]; reused as uint stage [64 e][stride 132]
    const int tid = threadIdx.x;
    const float4* wsrc = (const float4*)(WEP + (size_t)bh * 4096);
#pragma unroll
    for (int it = 0; it < 4; it++)
        ((float4*)weps)[it * 256 + tid] = wsrc[it * 256 + tid];
#pragma unroll
    for (int it = 0; it < 8; it++) {
        int g = it * 256 + tid;
        int r = g >> 4, c = (g & 15) * 4;
        *(float4*)&wqs[r * 68 + c] =
            *(const float4*)&Wq[(size_t)(Dt * 128 + r) * 1024 + h * 64 + c];
    }
    __syncthreads();
    const int Dloc = tid >> 1, e0 = (tid & 1) * 32;
    float acc[32];
#pragma unroll
    for (int e = 0; e < 32; e++) acc[e] = 0.f;
    for (int d = 0; d < 64; d++) {
        float a = wqs[Dloc * 68 + d];
        const float* wr = &weps[d * 64 + e0];
#pragma unroll
        for (int e = 0; e < 32; e++) acc[e] += a * wr[e];
    }
    __syncthreads();   // all wqs/weps reads done; reuse wqs as packed hi|lo stage
    unsigned* stage = (unsigned*)wqs;  // [64 e][stride 132]
#pragma unroll
    for (int e = 0; e < 32; e++) {
        float v = acc[e] * QWSCALE;
        bf16 hv = (bf16)v;
        bf16 lv = (bf16)(v - (float)hv);
        unsigned hb = *(unsigned short*)&hv;
        unsigned lb = *(unsigned short*)&lv;
        stage[(e0 + e) * 132 + Dloc] = hb | (lb << 16);
    }
    __syncthreads();
    {
        const int e = tid >> 2, c0 = (tid & 3) * 32;
        const unsigned* src = &stage[e * 132 + c0];
        bf16 hi32[32], lo32[32];
#pragma unroll
        for (int j = 0; j < 32; j++) {
            unsigned u = src[j];
            unsigned short hb = (unsigned short)(u & 0xffff);
            unsigned short lb = (unsigned short)(u >> 16);
            hi32[j] = *(bf16*)&hb;
            lo32[j] = *(bf16*)&lb;
        }
        size_t base = ((size_t)b * 1024 + h * 64 + e) * 1024 + Dt * 128 + c0;
#pragma unroll
        for (int q8 = 0; q8 < 4; q8++) {
            *(bf8v*)&Thi[base + q8 * 8] = *(bf8v*)&hi32[q8 * 8];
            *(bf8v*)&Tlo[base + q8 * 8] = *(bf8v*)&lo32[q8 * 8];
        }
    }
}

// ---------------- split/cast fp32 -> bf16 hi (+lo) ----------------
__global__ void split_cast_k(const float* __restrict__ x, bf16* __restrict__ hi,
                             bf16* __restrict__ lo, int n4)
{
    int idx = blockIdx.x * blockDim.x + threadIdx.x;
    int stride = gridDim.x * blockDim.x;
    for (int i = idx; i < n4; i += stride) {
        float4 v = ((const float4*)x)[i];
        bf4v h;
        h[0] = (bf16)v.x; h[1] = (bf16)v.y; h[2] = (bf16)v.z; h[3] = (bf16)v.w;
        ((bf4v*)hi)[i] = h;
        if (lo) {
            bf4v l;
            l[0] = (bf16)(v.x - (float)h[0]);
            l[1] = (bf16)(v.y - (float)h[1]);
            l[2] = (bf16)(v.z - (float)h[2]);
            l[3] = (bf16)(v.w - (float)h[3]);
            ((bf4v*)lo)[i] = l;
        }
    }
}

// ------- transpose fp32 W[k][n] -> bf16 WT[n][k] (1024x1024), optional hi/lo split -------
__global__ __launch_bounds__(256) void transw_k(const float* __restrict__ W,
                                                bf16* __restrict__ WT, bf16* __restrict__ WTlo)
{
    __shared__ float T[64 * 68];
    const int k0 = blockIdx.x * 64, n0 = blockIdx.y * 64;
    const int tid = threadIdx.x;
#pragma unroll
    for (int it = 0; it < 4; it++) {
        int g = it * 256 + tid;
        int r = g >> 4, c = (g & 15) * 4;
        *(float4*)&T[r * 68 + c] = *(const float4*)&W[(size_t)(k0 + r) * 1024 + n0 + c];
    }
    __syncthreads();
#pragma unroll
    for (int it = 0; it < 4; it++) {
        int g = it * 256 + tid;
        int n = g >> 4, k4 = (g & 15) * 4;
        bf4v o, ol;
#pragma unroll
        for (int t = 0; t < 4; t++) {
            float v = T[(k4 + t) * 68 + n];
            o[t] = (bf16)v;
            ol[t] = (bf16)(v - (float)o[t]);
        }
        *(bf4v*)&WT[(size_t)(n0 + n) * 1024 + k0 + k4] = o;
        if (WTlo) *(bf4v*)&WTlo[(size_t)(n0 + n) * 1024 + k0 + k4] = ol;
    }
}

// ---------------- bf16 MFMA GEMM: C[m][n] = A[m][k] @ Bt[n][k]^T, M=8192, N=K=1024 ----------------
// PASSES=3: A and B both hi/lo split: acc = AhiBhi + AloBhi + AhiBlo (drop lo*lo).
// outmode 0: fp32 out[m*1024+n] + bias[n]
// outmode 1: split-headed bf16: outH/outL[((b*16+h)*1024+l)*64+e]
// outmode 2: VT bf16: outH[((b*16+h)*64+d)*1024+s]
template<int PASSES>
__global__ __launch_bounds__(256, 2) void gemm_k(
    const bf16* __restrict__ A, const bf16* __restrict__ Alo,
    const bf16* __restrict__ Bt, const bf16* __restrict__ Btlo,
    int bBatched, int outmode,
    float* __restrict__ outF, const float* __restrict__ bias,
    bf16* __restrict__ outH, bf16* __restrict__ outL)
{
    __shared__ bf16 Ah[128 * 64];
    __shared__ bf16 Bh[128 * 64];
    __shared__ bf16 Al[(PASSES == 3) ? 128 * 64 : 64];
    __shared__ bf16 Bl[(PASSES == 3) ? 128 * 64 : 64];
    const int tid = threadIdx.x;
    const int bm = blockIdx.x, bn = blockIdx.y;
    const size_t boff = bBatched ? ((size_t)(bm >> 3) << 20) : (size_t)0;
    const bf16* Bt_b = Bt + boff;
    const bf16* Btlo_b = (PASSES == 3) ? (Btlo + boff) : nullptr;
    const int li = tid & 15;
    const int qq = (tid >> 4) & 3;
    const int wave = tid >> 6;
    const int wm0 = (wave & 1) * 64, wn0 = (wave >> 1) * 64;

    f4v acc[4][4];
    f4v zf; zf[0] = 0.f; zf[1] = 0.f; zf[2] = 0.f; zf[3] = 0.f;
#pragma unroll
    for (int mt = 0; mt < 4; mt++)
#pragma unroll
        for (int nt = 0; nt < 4; nt++) acc[mt][nt] = zf;

    for (int kt = 0; kt < 16; kt++) {
        const int col0 = kt * 64;
#pragma unroll
        for (int it = 0; it < 4; it++) {
            int g = it * 256 + tid;
            int r = g >> 3, p = g & 7;
            int gcol = col0 + ((p ^ (r & 7)) << 3);
            int ldsoff = (g & ~63) << 3;
            size_t ga = (size_t)(bm * 128 + r) * 1024 + gcol;
            size_t gb = (size_t)(bn * 128 + r) * 1024 + gcol;
            glds16(Ah + ldsoff, A + ga);
            glds16(Bh + ldsoff, Bt_b + gb);
            if (PASSES == 3) {
                glds16(Al + ldsoff, Alo + ga);
                glds16(Bl + ldsoff, Btlo_b + gb);
            }
        }
        __syncthreads();
#pragma unroll
        for (int ks = 0; ks < 2; ks++) {
            s8v af[4], alf[4], bhf[4], blf[4];
#pragma unroll
            for (int mt = 0; mt < 4; mt++) {
                int row = wm0 + mt * 16 + li;
                int off = row * 64 + (((ks * 4 + qq) ^ (li & 7)) << 3);
                af[mt] = *(const s8v*)&Ah[off];
                if (PASSES == 3) alf[mt] = *(const s8v*)&Al[off];
            }
#pragma unroll
            for (int nt = 0; nt < 4; nt++) {
                int row = wn0 + nt * 16 + li;
                int off = row * 64 + (((ks * 4 + qq) ^ (li & 7)) << 3);
                bhf[nt] = *(const s8v*)&Bh[off];
                if (PASSES == 3) blf[nt] = *(const s8v*)&Bl[off];
            }
#pragma unroll
            for (int mt = 0; mt < 4; mt++)
#pragma unroll
                for (int nt = 0; nt < 4; nt++) {
                    acc[mt][nt] = __builtin_amdgcn_mfma_f32_16x16x32_bf16(
                        af[mt], bhf[nt], acc[mt][nt], 0, 0, 0);
                    if (PASSES == 3) {
                        acc[mt][nt] = __builtin_amdgcn_mfma_f32_16x16x32_bf16(
                            alf[mt], bhf[nt], acc[mt][nt], 0, 0, 0);
                        acc[mt][nt] = __builtin_amdgcn_mfma_f32_16x16x32_bf16(
                            af[mt], blf[nt], acc[mt][nt], 0, 0, 0);
                    }
                }
        }
        __syncthreads();
    }

    // epilogue
#pragma unroll
    for (int mt = 0; mt < 4; mt++) {
#pragma unroll
        for (int nt = 0; nt < 4; nt++) {
            int n = bn * 128 + wn0 + nt * 16 + li;
            int m0 = bm * 128 + wm0 + mt * 16 + qq * 4;
            if (outmode == 0) {
                float bv = bias[n];
#pragma unroll
                for (int rg = 0; rg < 4; rg++)
                    outF[(size_t)(m0 + rg) * 1024 + n] = acc[mt][nt][rg] + bv;
            } else if (outmode == 1) {
                int h = n >> 6, e = n & 63;
#pragma unroll
                for (int rg = 0; rg < 4; rg++) {
                    int m = m0 + rg;
                    int b = m >> 10, l = m & 1023;
                    size_t idx = ((size_t)(b * NH + h) * 1024 + l) * 64 + e;
                    float v = acc[mt][nt][rg];
                    bf16 hv = (bf16)v;
                    outH[idx] = hv;
                    outL[idx] = (bf16)(v - (float)hv);
                }
            } else {
                int b = m0 >> 10, s = m0 & 1023;
                int h = n >> 6, d = n & 63;
                bf4v v;
                v[0] = (bf16)acc[mt][nt][0]; v[1] = (bf16)acc[mt][nt][1];
                v[2] = (bf16)acc[mt][nt][2]; v[3] = (bf16)acc[mt][nt][3];
                *(bf4v*)&outH[((size_t)(b * NH + h) * 64 + d) * 1024 + s] = v;
            }
        }
    }
}

// ---------------- fused attention: S^T = Kp·Qw^T 3-pass, online softmax, O^T = V^T·P^T ----------------
// Output layout honors the reference's reshape quirk: O[b][h*64+d][l]  (K-dim of final GEMM = l)
__global__ __launch_bounds__(256, 2) void attn_k(
    const bf16* __restrict__ QwHi, const bf16* __restrict__ QwLo,
    const bf16* __restrict__ KpHi, const bf16* __restrict__ KpLo,
    const bf16* __restrict__ VT, bf16* __restrict__ O)
{
    __shared__ bf16 Qh[128 * 64];
    __shared__ bf16 Ql[128 * 64];
    __shared__ __align__(16) char scratch[43008];
    bf16* Kh = (bf16*)scratch;          // [64][64]
    bf16* Kl = Kh + 4096;               // [64][64]
    bf16* Vt = Kh + 8192;               // [64 d][64 s]
    bf16* Pb = Kh + 12288;              // [128 r][stride 72]
    float* Obuf = (float*)scratch;      // [64 d][stride 132] (epilogue reuse)

    const int tid = threadIdx.x;
    const int l0 = blockIdx.x * 128;
    const int bh = blockIdx.z * NH + blockIdx.y;
    const int li = tid & 15;
    const int qq = (tid >> 4) & 3;
    const int wave = tid >> 6;
    const int r0w = wave * 32;

    // prologue: stage Qw hi/lo tile [128 l][64 e] (xor-swizzled)
    const bf16* qhsrc = QwHi + ((size_t)bh * 1024 + l0) * 64;
    const bf16* qlsrc = QwLo + ((size_t)bh * 1024 + l0) * 64;
#pragma unroll
    for (int it = 0; it < 8; it++) {
        int g = it * 256 + tid;
        int buf = g >> 10;
        int L = g & 1023;
        int r = L >> 3, p = L & 7;
        int goff = r * 64 + ((p ^ (r & 7)) << 3);
        glds16((buf ? Ql : Qh) + ((L & ~63) << 3), (buf ? qlsrc : qhsrc) + goff);
    }

    float mrun[2], lsum[2];
    mrun[0] = -__builtin_inff(); mrun[1] = -__builtin_inff();
    lsum[0] = 0.f; lsum[1] = 0.f;
    f4v accO[4][2];
    {
        f4v zf; zf[0] = 0.f; zf[1] = 0.f; zf[2] = 0.f; zf[3] = 0.f;
#pragma unroll
        for (int dt = 0; dt < 4; dt++) { accO[dt][0] = zf; accO[dt][1] = zf; }
    }

    for (int s0 = 0; s0 < 1024; s0 += 64) {
        __syncthreads();  // previous chunk's K/V/P reads done (also drains prologue loads)
#pragma unroll
        for (int it = 0; it < 6; it++) {
            int g = it * 256 + tid;
            int buf = g >> 9;
            int L = g & 511;
            int r = L >> 3, p = L & 7;
            int blk = (p ^ (r & 7)) << 3;
            const bf16* src;
            bf16* dstb;
            if (buf == 0)      { src = KpHi + ((size_t)bh * 1024 + s0 + r) * 64 + blk; dstb = Kh; }
            else if (buf == 1) { src = KpLo + ((size_t)bh * 1024 + s0 + r) * 64 + blk; dstb = Kl; }
            else               { src = VT + ((size_t)bh * 64 + r) * 1024 + s0 + blk;   dstb = Vt; }
            glds16(dstb + ((L & ~63) << 3), src);
        }
        __syncthreads();

        // scores: accS[ct][rt] = S^T tile; S^T rows c = ct*16+qq*4+rg, cols r = r0w+rt*16+li
        f4v accS[4][2];
        {
            f4v zf; zf[0] = 0.f; zf[1] = 0.f; zf[2] = 0.f; zf[3] = 0.f;
#pragma unroll
            for (int ct = 0; ct < 4; ct++) { accS[ct][0] = zf; accS[ct][1] = zf; }
        }
#pragma unroll
        for (int ks = 0; ks < 2; ks++) {
            s8v khf[4], klf[4], qhf[2], qlf[2];
#pragma unroll
            for (int ct = 0; ct < 4; ct++) {
                int row = ct * 16 + li;
                int off = row * 64 + (((ks * 4 + qq) ^ (li & 7)) << 3);
                khf[ct] = *(const s8v*)&Kh[off];
                klf[ct] = *(const s8v*)&Kl[off];
            }
#pragma unroll
            for (int rt = 0; rt < 2; rt++) {
                int row = r0w + rt * 16 + li;
                int off = row * 64 + (((ks * 4 + qq) ^ (li & 7)) << 3);
                qhf[rt] = *(const s8v*)&Qh[off];
                qlf[rt] = *(const s8v*)&Ql[off];
            }
#pragma unroll
            for (int ct = 0; ct < 4; ct++)
#pragma unroll
                for (int rt = 0; rt < 2; rt++) {
                    accS[ct][rt] = __builtin_amdgcn_mfma_f32_16x16x32_bf16(
                        khf[ct], qhf[rt], accS[ct][rt], 0, 0, 0);
                    accS[ct][rt] = __builtin_amdgcn_mfma_f32_16x16x32_bf16(
                        khf[ct], qlf[rt], accS[ct][rt], 0, 0, 0);
                    accS[ct][rt] = __builtin_amdgcn_mfma_f32_16x16x32_bf16(
                        klf[ct], qhf[rt], accS[ct][rt], 0, 0, 0);
                }
        }

        // online softmax (exp2 domain, scale pre-folded); row r owned by lanes with same li
#pragma unroll
        for (int rt = 0; rt < 2; rt++) {
            float mx = -1e30f;
#pragma unroll
            for (int ct = 0; ct < 4; ct++)
#pragma unroll
                for (int rg = 0; rg < 4; rg++) mx = fmaxf(mx, accS[ct][rt][rg]);
            mx = fmaxf(mx, __shfl_xor(mx, 16));
            mx = fmaxf(mx, __shfl_xor(mx, 32));
            float mnew = fmaxf(mrun[rt], mx);
            float alpha = exp2f(mrun[rt] - mnew);
            float ls = 0.f;
            int prow = r0w + rt * 16 + li;
#pragma unroll
            for (int ct = 0; ct < 4; ct++) {
                bf4v pv;
#pragma unroll
                for (int rg = 0; rg < 4; rg++) {
                    float p_ = exp2f(accS[ct][rt][rg] - mnew);
                    ls += p_;
                    pv[rg] = (bf16)p_;
                }
                *(bf4v*)&Pb[prow * 72 + ct * 16 + qq * 4] = pv;
            }
            ls += __shfl_xor(ls, 16);
            ls += __shfl_xor(ls, 32);
            lsum[rt] = lsum[rt] * alpha + ls;
            mrun[rt] = mnew;
#pragma unroll
            for (int dt = 0; dt < 4; dt++)
#pragma unroll
                for (int rg = 0; rg < 4; rg++) accO[dt][rt][rg] *= alpha;
        }
        asm volatile("" ::: "memory");  // keep P ds_writes before PV ds_reads (wave-private rows)

        // PV: accO[dt][rt] = O^T tile [d][r]
#pragma unroll
        for (int ks = 0; ks < 2; ks++) {
            s8v vf[4], pf[2];
#pragma unroll
            for (int dt = 0; dt < 4; dt++) {
                int row = dt * 16 + li;
                int off = row * 64 + (((ks * 4 + qq) ^ (li & 7)) << 3);
                vf[dt] = *(const s8v*)&Vt[off];
            }
#pragma unroll
            for (int rt = 0; rt < 2; rt++) {
                int row = r0w + rt * 16 + li;
                pf[rt] = *(const s8v*)&Pb[row * 72 + ks * 32 + qq * 8];
            }
#pragma unroll
            for (int dt = 0; dt < 4; dt++)
#pragma unroll
                for (int rt = 0; rt < 2; rt++)
                    accO[dt][rt] = __builtin_amdgcn_mfma_f32_16x16x32_bf16(
                        vf[dt], pf[rt], accO[dt][rt], 0, 0, 0);
        }
    }

    // epilogue: normalize; accO holds O^T[d = dt*16+qq*4+rg][r = r0w+rt*16+li] -- already the
    // orientation the reference's reshape quirk needs. Stage fp32 O^T in LDS, store bf16 rows.
    __syncthreads();
#pragma unroll
    for (int rt = 0; rt < 2; rt++) {
        float inv = 1.f / lsum[rt];
        int rr = r0w + rt * 16 + li;
#pragma unroll
        for (int dt = 0; dt < 4; dt++)
#pragma unroll
            for (int rg = 0; rg < 4; rg++)
                Obuf[(dt * 16 + qq * 4 + rg) * 132 + rr] = accO[dt][rt][rg] * inv;
    }
    __syncthreads();
    {
        int d = tid >> 2, c0 = (tid & 3) * 32;
        const float* src = &Obuf[d * 132 + c0];
        bf16* dst = O + ((size_t)blockIdx.z * 1024 + blockIdx.y * 64 + d) * 1024 + l0 + c0;
#pragma unroll
        for (int q8 = 0; q8 < 4; q8++) {
            bf8v o;
#pragma unroll
            for (int j = 0; j < 8; j++) o[j] = (bf16)src[q8 * 8 + j];
            *(bf8v*)&dst[q8 * 8] = o;
        }
    }
}

extern "C" void kernel_launch(void* const* d_in, const int* in_sizes, int n_in,
                              void* d_out, int out_size, void* d_ws, size_t ws_size,
                              hipStream_t stream) {
    const float* queries = (const float*)d_in[0];
    const float* keys    = (const float*)d_in[1];
    const float* values  = (const float*)d_in[2];
    const float* routers = (const float*)d_in[3];
    const float* Wq  = (const float*)d_in[4];
    const float* Wk  = (const float*)d_in[5];
    const float* Wv  = (const float*)d_in[6];
    const float* Wlq = (const float*)d_in[7];
    const float* Wlk = (const float*)d_in[8];
    const float* Wo  = (const float*)d_in[9];
    const float* bo  = (const float*)d_in[10];
    float* out = (float*)d_out;

    // workspace: 6 x 16.78MB big buffers + 14.7MB small = ~115.3 MB (140.5 MB proven in round 1)
    char* w = (char*)d_ws;
    const size_t BIG = 16777216;
    bf16* QwHi = (bf16*)(w);
    bf16* QwLo = (bf16*)(w + 1 * BIG);
    bf16* Thi  = (bf16*)(w + 2 * BIG);   // WqWepT hi -> reused as KpHi
    bf16* Tlo  = (bf16*)(w + 3 * BIG);   // WqWepT lo -> reused as KpLo
    bf16* actHi = (bf16*)(w + 4 * BIG);  // split activations -> reused as attn out Obf
    bf16* actLo = (bf16*)(w + 5 * BIG);  // split activations -> reused as VT
    char* w2 = w + 6 * BIG;
    const size_t SM = 2097152;
    bf16*  WkThi = (bf16*)(w2);
    bf16*  WkTlo = (bf16*)(w2 + 1 * SM);
    bf16*  WvT   = (bf16*)(w2 + 2 * SM);
    bf16*  WoT   = (bf16*)(w2 + 3 * SM);
    float* RQ    = (float*)(w2 + 4 * SM);
    float* RK    = (float*)(w2 + 5 * SM);
    float* WEP   = (float*)(w2 + 6 * SM);
    bf16* KpHi = Thi;
    bf16* KpLo = Tlo;
    bf16* VTp  = actLo;
    bf16* Obf  = actHi;

    dim3 blk(256);
    // weight prep
    transw_k<<<dim3(16, 16), blk, 0, stream>>>(Wk, WkThi, WkTlo);
    transw_k<<<dim3(16, 16), blk, 0, stream>>>(Wv, WvT, nullptr);
    transw_k<<<dim3(16, 16), blk, 0, stream>>>(Wo, WoT, nullptr);
    // router path (fp32 exact): both projections in one 256-block launch
    rgemm_k<<<dim3(8, 32), blk, 0, stream>>>(routers, Wlq, Wlk, RQ, RK);
    wep_k<<<dim3(BB * NH), blk, 0, stream>>>(RQ, RK, WEP);
    wqwep_k<<<dim3(BB * NH, 8), blk, 0, stream>>>(Wq, WEP, Thi, Tlo);
    // Qw = queries @ (Wq Wep)[b], 3-pass split x split, split-headed out
    split_cast_k<<<1024, blk, 0, stream>>>(queries, actHi, actLo, 2097152);
    gemm_k<3><<<dim3(64, 8), blk, 0, stream>>>(actHi, actLo, Thi, Tlo, 1, 1,
                                               nullptr, nullptr, QwHi, QwLo);
    // Kp = keys @ Wk, 3-pass split x split, split-headed out (overwrites Thi/Tlo)
    split_cast_k<<<1024, blk, 0, stream>>>(keys, actHi, actLo, 2097152);
    gemm_k<3><<<dim3(64, 8), blk, 0, stream>>>(actHi, actLo, WkThi, WkTlo, 0, 1,
                                               nullptr, nullptr, KpHi, KpLo);
    // V^T = (values @ Wv)^T, plain bf16 (error negligible on V path)
    split_cast_k<<<1024, blk, 0, stream>>>(values, actHi, nullptr, 2097152);
    gemm_k<1><<<dim3(64, 8), blk, 0, stream>>>(actHi, nullptr, WvT, nullptr, 0, 2,
                                               nullptr, nullptr, VTp, nullptr);
    // fused attention -> O^T quirk layout [b][h*64+d][l]
    attn_k<<<dim3(8, NH, BB), blk, 0, stream>>>(QwHi, QwLo, KpHi, KpLo, VTp, Obf);
    // out = Obf @ Wo + bo (fp32 out)
    gemm_k<1><<<dim3(64, 8), blk, 0, stream>>>(Obf, nullptr, WoT, nullptr, 0, 0,
                                               out, bo, nullptr, nullptr);
}